// Round 1
// baseline (2546.442 us; speedup 1.0000x reference)
//
#include <hip/hip_runtime.h>

// ---------------------------------------------------------------------------
// BikeSafetyGNN: 3-layer GraphSAGE (mean) + 2 linear heads, fp32.
// Strategy:
//   - project-before-aggregate: agg traffic is E*dout not E*din
//   - CSR built once per call (int atomics only), reused for all 3 layers
//   - per-node gather with 4 independent accumulator chains (MLP), no fp atomics
//   - W^T staged in LDS as [k/4][c][4] so lanes read float4 conflict-free
// ---------------------------------------------------------------------------

__global__ __launch_bounds__(256) void k_deg(const int* __restrict__ dst, int E,
                                             int* __restrict__ deg, int N) {
    int i = blockIdx.x * 256 + threadIdx.x;
    if (i < E) {
        int d = dst[i];
        d = d < 0 ? 0 : (d >= N ? N - 1 : d);
        atomicAdd(&deg[d], 1);
    }
}

// ---- 2-level exclusive scan over deg[N] -> rowptr[N+1], chunk = 2048 ----
__global__ __launch_bounds__(256) void k_scan_partial(const int* __restrict__ deg,
                                                      int N, int* __restrict__ sums) {
    __shared__ int sd[256];
    int base = blockIdx.x * 2048 + threadIdx.x * 8;
    int s = 0;
    #pragma unroll
    for (int i = 0; i < 8; ++i) { int idx = base + i; if (idx < N) s += deg[idx]; }
    sd[threadIdx.x] = s; __syncthreads();
    for (int off = 128; off > 0; off >>= 1) {
        if (threadIdx.x < off) sd[threadIdx.x] += sd[threadIdx.x + off];
        __syncthreads();
    }
    if (threadIdx.x == 0) sums[blockIdx.x] = sd[0];
}

__global__ __launch_bounds__(256) void k_scan_offsets(int* __restrict__ sums, int NB) {
    __shared__ int sd[256];
    int tid = threadIdx.x;
    int v = (tid < NB) ? sums[tid] : 0;
    sd[tid] = v; __syncthreads();
    for (int off = 1; off < 256; off <<= 1) {
        int t = (tid >= off) ? sd[tid - off] : 0;
        __syncthreads();
        sd[tid] += t;
        __syncthreads();
    }
    if (tid < NB) sums[tid] = sd[tid] - v;   // exclusive
}

__global__ __launch_bounds__(256) void k_scan_final(const int* __restrict__ deg, int N,
                                                    const int* __restrict__ sums,
                                                    int* __restrict__ rowptr, int E) {
    __shared__ int sd[256];
    int tid = threadIdx.x;
    int base = blockIdx.x * 2048 + tid * 8;
    int v[8]; int s = 0;
    #pragma unroll
    for (int i = 0; i < 8; ++i) { int idx = base + i; v[i] = (idx < N) ? deg[idx] : 0; s += v[i]; }
    sd[tid] = s; __syncthreads();
    for (int off = 1; off < 256; off <<= 1) {
        int t = (tid >= off) ? sd[tid - off] : 0;
        __syncthreads();
        sd[tid] += t;
        __syncthreads();
    }
    int run = sums[blockIdx.x] + sd[tid] - s;  // exclusive prefix for this thread
    #pragma unroll
    for (int i = 0; i < 8; ++i) { int idx = base + i; if (idx < N) rowptr[idx] = run; run += v[i]; }
    if (blockIdx.x == 0 && tid == 0) rowptr[N] = E;
}

__global__ __launch_bounds__(256) void k_fill(const int* __restrict__ src,
                                              const int* __restrict__ dst, int E,
                                              const int* __restrict__ rowptr,
                                              int* __restrict__ cursor,
                                              int* __restrict__ adj, int N) {
    int i = blockIdx.x * 256 + threadIdx.x;
    if (i < E) {
        int d = dst[i];
        d = d < 0 ? 0 : (d >= N ? N - 1 : d);
        int s = src[i];
        s = s < 0 ? 0 : (s >= N ? N - 1 : s);
        int pos = rowptr[d] + atomicAdd(&cursor[d], 1);
        adj[pos] = s;
    }
}

// ---- P = H @ W^T   (W is [DOUT][DIN] row-major) ----
template<int DIN, int DOUT>
__global__ __launch_bounds__(256) void proj_kernel(const float* __restrict__ H,
                                                   const float* __restrict__ W,
                                                   float* __restrict__ P, int N) {
    constexpr int SUBS = 64 / DOUT;   // node subgroups per wave
    constexpr int M = 4;              // node-iterations per thread
    constexpr int NPW = SUBS * M;
    constexpr int NPB = NPW * 4;      // 4 waves/block
    __shared__ float wt[DIN * DOUT];  // [k/4][c][4]
    for (int idx = threadIdx.x; idx < DIN * DOUT; idx += 256) {
        int c = idx / DIN, k = idx % DIN;
        wt[(k >> 2) * (DOUT * 4) + c * 4 + (k & 3)] = W[idx];
    }
    __syncthreads();
    const int wave = threadIdx.x >> 6, lane = threadIdx.x & 63;
    const int c = lane % DOUT, sub = lane / DOUT;
    const int nodebase = blockIdx.x * NPB + wave * NPW + sub;
    int nm[M]; bool vm[M];
    #pragma unroll
    for (int m = 0; m < M; ++m) {
        int n = nodebase + m * SUBS;
        vm[m] = (n < N);
        nm[m] = vm[m] ? n : 0;
    }
    float acc[M] = {};
    const float4* wt4 = (const float4*)wt;
    for (int k4 = 0; k4 < DIN / 4; ++k4) {
        float4 w = wt4[k4 * DOUT + c];
        #pragma unroll
        for (int m = 0; m < M; ++m) {
            float4 h = ((const float4*)(H + (size_t)nm[m] * DIN))[k4];
            acc[m] += w.x * h.x + w.y * h.y + w.z * h.z + w.w * h.w;
        }
    }
    #pragma unroll
    for (int m = 0; m < M; ++m)
        if (vm[m]) P[(size_t)nm[m] * DOUT + c] = acc[m];
}

// ---- Hout = relu( mean_agg(P) + H @ Wr^T + b ) ----
template<int DIN, int DOUT>
__global__ __launch_bounds__(256) void agg_kernel(const float* __restrict__ P,
                                                  const float* __restrict__ H,
                                                  const float* __restrict__ Wr,
                                                  const float* __restrict__ bias,
                                                  const int* __restrict__ rowptr,
                                                  const int* __restrict__ adj,
                                                  float* __restrict__ Hout, int N) {
    constexpr int SUBS = 64 / DOUT;
    constexpr int M = 4;
    constexpr int NPW = SUBS * M;
    constexpr int NPB = NPW * 4;
    __shared__ float wt[DIN * DOUT];
    for (int idx = threadIdx.x; idx < DIN * DOUT; idx += 256) {
        int c = idx / DIN, k = idx % DIN;
        wt[(k >> 2) * (DOUT * 4) + c * 4 + (k & 3)] = Wr[idx];
    }
    __syncthreads();
    const int wave = threadIdx.x >> 6, lane = threadIdx.x & 63;
    const int c = lane % DOUT, sub = lane / DOUT;
    const int nodebase = blockIdx.x * NPB + wave * NPW + sub;
    int nm[M]; bool vm[M];
    #pragma unroll
    for (int m = 0; m < M; ++m) {
        int n = nodebase + m * SUBS;
        vm[m] = (n < N);
        nm[m] = vm[m] ? n : 0;
    }
    float aggv[M];
    #pragma unroll
    for (int m = 0; m < M; ++m) {
        int n = nm[m];
        int beg = rowptr[n], end = rowptr[n + 1];
        float a0 = 0.f, a1 = 0.f, a2 = 0.f, a3 = 0.f;   // 4 chains for MLP
        int j = beg;
        for (; j + 4 <= end; j += 4) {
            int s0 = adj[j], s1 = adj[j + 1], s2 = adj[j + 2], s3 = adj[j + 3];
            a0 += P[(size_t)s0 * DOUT + c];
            a1 += P[(size_t)s1 * DOUT + c];
            a2 += P[(size_t)s2 * DOUT + c];
            a3 += P[(size_t)s3 * DOUT + c];
        }
        for (; j < end; ++j) a0 += P[(size_t)adj[j] * DOUT + c];
        int deg = end - beg;
        float inv = deg > 0 ? 1.0f / (float)deg : 0.0f;   // max(cnt,1): deg=0 -> mean 0
        aggv[m] = (a0 + a1 + a2 + a3) * inv;
    }
    float r[M] = {};
    const float4* wt4 = (const float4*)wt;
    for (int k4 = 0; k4 < DIN / 4; ++k4) {
        float4 w = wt4[k4 * DOUT + c];
        #pragma unroll
        for (int m = 0; m < M; ++m) {
            float4 h = ((const float4*)(H + (size_t)nm[m] * DIN))[k4];
            r[m] += w.x * h.x + w.y * h.y + w.z * h.z + w.w * h.w;
        }
    }
    float bc = bias[c];
    #pragma unroll
    for (int m = 0; m < M; ++m)
        if (vm[m]) Hout[(size_t)nm[m] * DOUT + c] = fmaxf(aggv[m] + r[m] + bc, 0.0f);
}

__global__ __launch_bounds__(256) void k_head(const float* __restrict__ H3,
                                              const float* __restrict__ Wreg,
                                              const float* __restrict__ breg,
                                              const float* __restrict__ Wcls,
                                              const float* __restrict__ bcls,
                                              float* __restrict__ out, int N) {
    int i = blockIdx.x * 256 + threadIdx.x;
    if (i >= N) return;
    const float4* h = (const float4*)(H3 + (size_t)i * 16);
    float reg = 0.f, cls = 0.f;
    #pragma unroll
    for (int k4 = 0; k4 < 4; ++k4) {
        float4 hv = h[k4];
        float4 wr = ((const float4*)Wreg)[k4];
        float4 wc = ((const float4*)Wcls)[k4];
        reg += hv.x * wr.x + hv.y * wr.y + hv.z * wr.z + hv.w * wr.w;
        cls += hv.x * wc.x + hv.y * wc.y + hv.z * wc.z + hv.w * wc.w;
    }
    out[i] = reg + breg[0];
    out[(size_t)N + i] = cls + bcls[0];
}

extern "C" void kernel_launch(void* const* d_in, const int* in_sizes, int n_in,
                              void* d_out, int out_size, void* d_ws, size_t ws_size,
                              hipStream_t stream) {
    const float* x    = (const float*)d_in[0];
    const int*   ei   = (const int*)d_in[1];
    const float* W1l  = (const float*)d_in[2];
    const float* b1l  = (const float*)d_in[3];
    const float* W1r  = (const float*)d_in[4];
    const float* W2l  = (const float*)d_in[5];
    const float* b2l  = (const float*)d_in[6];
    const float* W2r  = (const float*)d_in[7];
    const float* W3l  = (const float*)d_in[8];
    const float* b3l  = (const float*)d_in[9];
    const float* W3r  = (const float*)d_in[10];
    const float* Wreg = (const float*)d_in[11];
    const float* breg = (const float*)d_in[12];
    const float* Wcls = (const float*)d_in[13];
    const float* bcls = (const float*)d_in[14];

    const int N = in_sizes[0] / 128;
    const int E = in_sizes[1] / 2;
    const int* src = ei;
    const int* dst = ei + E;

    char* ws = (char*)d_ws;
    size_t off = 0;
    auto alloc = [&](size_t bytes) -> void* {
        void* p = ws + off;
        off += (bytes + 255) & ~(size_t)255;
        return p;
    };
    int*   rowptr = (int*)alloc((size_t)(N + 1) * 4);
    int*   deg    = (int*)alloc((size_t)N * 4);       // also reused as fill cursor
    int*   sums   = (int*)alloc(1024);
    int*   adj    = (int*)alloc((size_t)E * 4);
    float* A      = (float*)alloc((size_t)N * 64 * 4);  // projected-l buffer
    float* B      = (float*)alloc((size_t)N * 64 * 4);  // h1
    float* C      = (float*)alloc((size_t)N * 32 * 4);  // h2
    float* D      = (float*)alloc((size_t)N * 16 * 4);  // h3

    const int gE = (E + 255) / 256;
    const int NB = (N + 2047) / 2048;   // 98 for N=200000 (fits single-block level-2 scan)

    // ---- CSR build (once, reused by all 3 layers) ----
    hipMemsetAsync(deg, 0, (size_t)N * 4, stream);
    k_deg<<<gE, 256, 0, stream>>>(dst, E, deg, N);
    k_scan_partial<<<NB, 256, 0, stream>>>(deg, N, sums);
    k_scan_offsets<<<1, 256, 0, stream>>>(sums, NB);
    k_scan_final<<<NB, 256, 0, stream>>>(deg, N, sums, rowptr, E);
    hipMemsetAsync(deg, 0, (size_t)N * 4, stream);
    k_fill<<<gE, 256, 0, stream>>>(src, dst, E, rowptr, deg, adj, N);

    // ---- layer 1: 128 -> 64 ----
    proj_kernel<128, 64><<<(N + 15) / 16, 256, 0, stream>>>(x, W1l, A, N);
    agg_kernel<128, 64><<<(N + 15) / 16, 256, 0, stream>>>(A, x, W1r, b1l, rowptr, adj, B, N);
    // ---- layer 2: 64 -> 32 ----
    proj_kernel<64, 32><<<(N + 31) / 32, 256, 0, stream>>>(B, W2l, A, N);
    agg_kernel<64, 32><<<(N + 31) / 32, 256, 0, stream>>>(A, B, W2r, b2l, rowptr, adj, C, N);
    // ---- layer 3: 32 -> 16 ----
    proj_kernel<32, 16><<<(N + 63) / 64, 256, 0, stream>>>(C, W3l, A, N);
    agg_kernel<32, 16><<<(N + 63) / 64, 256, 0, stream>>>(A, C, W3r, b3l, rowptr, adj, D, N);

    // ---- heads ----
    k_head<<<(N + 255) / 256, 256, 0, stream>>>(D, Wreg, breg, Wcls, bcls, (float*)d_out, N);
}

// Round 3
// 1828.278 us; speedup vs baseline: 1.3928x; 1.3928x over previous
//
#include <hip/hip_runtime.h>

// ---------------------------------------------------------------------------
// BikeSafetyGNN: 3-layer GraphSAGE (mean) + 2 linear heads, fp32.
// R3: fix gather grid size (R2 launched 4x too few blocks -> 3/4 of nodes
//     never aggregated). Grid now derived from the same constexpr as the
//     kernel's per-block node count.
// ---------------------------------------------------------------------------

__device__ __forceinline__ void f4add(float4& a, const float4 b) {
    a.x += b.x; a.y += b.y; a.z += b.z; a.w += b.w;
}

__global__ __launch_bounds__(256) void k_deg(const int* __restrict__ dst, int E,
                                             int* __restrict__ deg, int N) {
    int i = blockIdx.x * 256 + threadIdx.x;
    if (i < E) {
        int d = dst[i];
        d = d < 0 ? 0 : (d >= N ? N - 1 : d);
        atomicAdd(&deg[d], 1);
    }
}

// ---- 2-level exclusive scan over deg[N] -> rowptr[N+1], chunk = 2048 ----
__global__ __launch_bounds__(256) void k_scan_partial(const int* __restrict__ deg,
                                                      int N, int* __restrict__ sums) {
    __shared__ int sd[256];
    int base = blockIdx.x * 2048 + threadIdx.x * 8;
    int s = 0;
    #pragma unroll
    for (int i = 0; i < 8; ++i) { int idx = base + i; if (idx < N) s += deg[idx]; }
    sd[threadIdx.x] = s; __syncthreads();
    for (int off = 128; off > 0; off >>= 1) {
        if (threadIdx.x < off) sd[threadIdx.x] += sd[threadIdx.x + off];
        __syncthreads();
    }
    if (threadIdx.x == 0) sums[blockIdx.x] = sd[0];
}

__global__ __launch_bounds__(256) void k_scan_offsets(int* __restrict__ sums, int NB) {
    __shared__ int sd[256];
    int tid = threadIdx.x;
    int v = (tid < NB) ? sums[tid] : 0;
    sd[tid] = v; __syncthreads();
    for (int off = 1; off < 256; off <<= 1) {
        int t = (tid >= off) ? sd[tid - off] : 0;
        __syncthreads();
        sd[tid] += t;
        __syncthreads();
    }
    if (tid < NB) sums[tid] = sd[tid] - v;   // exclusive
}

__global__ __launch_bounds__(256) void k_scan_final(const int* __restrict__ deg, int N,
                                                    const int* __restrict__ sums,
                                                    int* __restrict__ rowptr, int E) {
    __shared__ int sd[256];
    int tid = threadIdx.x;
    int base = blockIdx.x * 2048 + tid * 8;
    int v[8]; int s = 0;
    #pragma unroll
    for (int i = 0; i < 8; ++i) { int idx = base + i; v[i] = (idx < N) ? deg[idx] : 0; s += v[i]; }
    sd[tid] = s; __syncthreads();
    for (int off = 1; off < 256; off <<= 1) {
        int t = (tid >= off) ? sd[tid - off] : 0;
        __syncthreads();
        sd[tid] += t;
        __syncthreads();
    }
    int run = sums[blockIdx.x] + sd[tid] - s;  // exclusive prefix for this thread
    #pragma unroll
    for (int i = 0; i < 8; ++i) { int idx = base + i; if (idx < N) rowptr[idx] = run; run += v[i]; }
    if (blockIdx.x == 0 && tid == 0) rowptr[N] = E;
}

__global__ __launch_bounds__(256) void k_fill(const int* __restrict__ src,
                                              const int* __restrict__ dst, int E,
                                              const int* __restrict__ rowptr,
                                              int* __restrict__ cursor,
                                              int* __restrict__ adj, int N) {
    int i = blockIdx.x * 256 + threadIdx.x;
    if (i < E) {
        int d = dst[i];
        d = d < 0 ? 0 : (d >= N ? N - 1 : d);
        int s = src[i];
        s = s < 0 ? 0 : (s >= N ? N - 1 : s);
        int pos = rowptr[d] + atomicAdd(&cursor[d], 1);
        adj[pos] = s;
    }
}

// ---- P = H @ W^T (+bias if non-null)   (W is [DOUT][DIN] row-major) ----
template<int DIN, int DOUT>
__global__ __launch_bounds__(256) void proj_kernel(const float* __restrict__ H,
                                                   const float* __restrict__ W,
                                                   const float* __restrict__ bias,
                                                   float* __restrict__ P, int N) {
    constexpr int SUBS = 64 / DOUT;   // node subgroups per wave
    constexpr int M = 4;              // node-iterations per thread
    constexpr int NPW = SUBS * M;
    constexpr int NPB = NPW * 4;      // 4 waves/block
    __shared__ float wt[DIN * DOUT];  // [k/4][c][4]
    for (int idx = threadIdx.x; idx < DIN * DOUT; idx += 256) {
        int c = idx / DIN, k = idx % DIN;
        wt[(k >> 2) * (DOUT * 4) + c * 4 + (k & 3)] = W[idx];
    }
    __syncthreads();
    const int wave = threadIdx.x >> 6, lane = threadIdx.x & 63;
    const int c = lane % DOUT, sub = lane / DOUT;
    const int nodebase = blockIdx.x * NPB + wave * NPW + sub;
    int nm[M]; bool vm[M];
    #pragma unroll
    for (int m = 0; m < M; ++m) {
        int n = nodebase + m * SUBS;
        vm[m] = (n < N);
        nm[m] = vm[m] ? n : 0;
    }
    float acc[M] = {};
    const float4* wt4 = (const float4*)wt;
    for (int k4 = 0; k4 < DIN / 4; ++k4) {
        float4 w = wt4[k4 * DOUT + c];
        #pragma unroll
        for (int m = 0; m < M; ++m) {
            float4 h = ((const float4*)(H + (size_t)nm[m] * DIN))[k4];
            acc[m] += w.x * h.x + w.y * h.y + w.z * h.z + w.w * h.w;
        }
    }
    float bc = bias ? bias[c] : 0.0f;
    #pragma unroll
    for (int m = 0; m < M; ++m)
        if (vm[m]) P[(size_t)nm[m] * DOUT + c] = acc[m] + bc;
}

// nodes-per-block constants shared between kernel and launch
template<int DOUT> struct GatherCfg {
    static constexpr int L   = DOUT / 4;   // lanes (float4s) per node row
    static constexpr int S   = 64 / L;     // nodes concurrently per wave
    static constexpr int M   = 4;          // sequential nodes per subgroup
    static constexpr int NPW = S * M;
    static constexpr int NPB = NPW * 4;    // 4 waves/block
};

// ---- Hout = relu( mean_{j in N(n)} P[j] + Hout[n] )   (in place; Hout holds R) ----
template<int DOUT>
__global__ __launch_bounds__(256, 6) void gather_kernel(const float* __restrict__ P,
                                                        const int* __restrict__ rowptr,
                                                        const int* __restrict__ adj,
                                                        float* __restrict__ Hout, int N) {
    using C = GatherCfg<DOUT>;
    constexpr int L = C::L;
    constexpr int S = C::S;
    constexpr int M = C::M;
    constexpr int NPW = C::NPW;
    constexpr int NPB = C::NPB;
    const int wave = threadIdx.x >> 6, lane = threadIdx.x & 63;
    const int sub = lane / L, cl = lane % L;
    const float4* __restrict__ P4 = (const float4*)P;
    float4* __restrict__ H4 = (float4*)Hout;
    const int base = blockIdx.x * NPB + wave * NPW + sub;
    #pragma unroll 1
    for (int m = 0; m < M; ++m) {
        int n = base + m * S;
        if (n >= N) continue;
        int beg = rowptr[n], end = rowptr[n + 1];
        float4 a0 = {0, 0, 0, 0}, a1 = {0, 0, 0, 0}, a2 = {0, 0, 0, 0}, a3 = {0, 0, 0, 0};
        int j = beg;
        // align j to 4 for int4 adjacency loads (adj base is 256B-aligned)
        while (j < end && (j & 3)) { f4add(a0, P4[(size_t)adj[j] * L + cl]); ++j; }
        for (; j + 8 <= end; j += 8) {
            int4 sA = *(const int4*)(adj + j);
            int4 sB = *(const int4*)(adj + j + 4);
            float4 p0 = P4[(size_t)sA.x * L + cl];
            float4 p1 = P4[(size_t)sA.y * L + cl];
            float4 p2 = P4[(size_t)sA.z * L + cl];
            float4 p3 = P4[(size_t)sA.w * L + cl];
            float4 p4 = P4[(size_t)sB.x * L + cl];
            float4 p5 = P4[(size_t)sB.y * L + cl];
            float4 p6 = P4[(size_t)sB.z * L + cl];
            float4 p7 = P4[(size_t)sB.w * L + cl];
            f4add(a0, p0); f4add(a1, p1); f4add(a2, p2); f4add(a3, p3);
            f4add(a0, p4); f4add(a1, p5); f4add(a2, p6); f4add(a3, p7);
        }
        if (j + 4 <= end) {
            int4 sA = *(const int4*)(adj + j);
            f4add(a0, P4[(size_t)sA.x * L + cl]);
            f4add(a1, P4[(size_t)sA.y * L + cl]);
            f4add(a2, P4[(size_t)sA.z * L + cl]);
            f4add(a3, P4[(size_t)sA.w * L + cl]);
            j += 4;
        }
        for (; j < end; ++j) f4add(a0, P4[(size_t)adj[j] * L + cl]);
        int deg = end - beg;
        float inv = deg > 0 ? 1.0f / (float)deg : 0.0f;
        float4 r = H4[(size_t)n * L + cl];
        float4 o;
        o.x = fmaxf((a0.x + a1.x + a2.x + a3.x) * inv + r.x, 0.0f);
        o.y = fmaxf((a0.y + a1.y + a2.y + a3.y) * inv + r.y, 0.0f);
        o.z = fmaxf((a0.z + a1.z + a2.z + a3.z) * inv + r.z, 0.0f);
        o.w = fmaxf((a0.w + a1.w + a2.w + a3.w) * inv + r.w, 0.0f);
        H4[(size_t)n * L + cl] = o;
    }
}

__global__ __launch_bounds__(256) void k_head(const float* __restrict__ H3,
                                              const float* __restrict__ Wreg,
                                              const float* __restrict__ breg,
                                              const float* __restrict__ Wcls,
                                              const float* __restrict__ bcls,
                                              float* __restrict__ out, int N) {
    int i = blockIdx.x * 256 + threadIdx.x;
    if (i >= N) return;
    const float4* h = (const float4*)(H3 + (size_t)i * 16);
    float reg = 0.f, cls = 0.f;
    #pragma unroll
    for (int k4 = 0; k4 < 4; ++k4) {
        float4 hv = h[k4];
        float4 wr = ((const float4*)Wreg)[k4];
        float4 wc = ((const float4*)Wcls)[k4];
        reg += hv.x * wr.x + hv.y * wr.y + hv.z * wr.z + hv.w * wr.w;
        cls += hv.x * wc.x + hv.y * wc.y + hv.z * wc.z + hv.w * wc.w;
    }
    out[i] = reg + breg[0];
    out[(size_t)N + i] = cls + bcls[0];
}

extern "C" void kernel_launch(void* const* d_in, const int* in_sizes, int n_in,
                              void* d_out, int out_size, void* d_ws, size_t ws_size,
                              hipStream_t stream) {
    const float* x    = (const float*)d_in[0];
    const int*   ei   = (const int*)d_in[1];
    const float* W1l  = (const float*)d_in[2];
    const float* b1l  = (const float*)d_in[3];
    const float* W1r  = (const float*)d_in[4];
    const float* W2l  = (const float*)d_in[5];
    const float* b2l  = (const float*)d_in[6];
    const float* W2r  = (const float*)d_in[7];
    const float* W3l  = (const float*)d_in[8];
    const float* b3l  = (const float*)d_in[9];
    const float* W3r  = (const float*)d_in[10];
    const float* Wreg = (const float*)d_in[11];
    const float* breg = (const float*)d_in[12];
    const float* Wcls = (const float*)d_in[13];
    const float* bcls = (const float*)d_in[14];

    const int N = in_sizes[0] / 128;
    const int E = in_sizes[1] / 2;
    const int* src = ei;
    const int* dst = ei + E;

    char* ws = (char*)d_ws;
    size_t off = 0;
    auto alloc = [&](size_t bytes) -> void* {
        void* p = ws + off;
        off += (bytes + 255) & ~(size_t)255;
        return p;
    };
    int*   rowptr = (int*)alloc((size_t)(N + 1) * 4);
    int*   deg    = (int*)alloc((size_t)N * 4);       // also reused as fill cursor
    int*   sums   = (int*)alloc(1024);
    int*   adj    = (int*)alloc((size_t)E * 4);
    float* A      = (float*)alloc((size_t)N * 64 * 4);  // projected-l buffer (P)
    float* B      = (float*)alloc((size_t)N * 64 * 4);  // h1
    float* C      = (float*)alloc((size_t)N * 32 * 4);  // h2
    float* D      = (float*)alloc((size_t)N * 16 * 4);  // h3

    const int gE = (E + 255) / 256;
    const int NB = (N + 2047) / 2048;   // 98 for N=200000

    // ---- CSR build (once, reused by all 3 layers) ----
    hipMemsetAsync(deg, 0, (size_t)N * 4, stream);
    k_deg<<<gE, 256, 0, stream>>>(dst, E, deg, N);
    k_scan_partial<<<NB, 256, 0, stream>>>(deg, N, sums);
    k_scan_offsets<<<1, 256, 0, stream>>>(sums, NB);
    k_scan_final<<<NB, 256, 0, stream>>>(deg, N, sums, rowptr, E);
    hipMemsetAsync(deg, 0, (size_t)N * 4, stream);
    k_fill<<<gE, 256, 0, stream>>>(src, dst, E, rowptr, deg, adj, N);

    constexpr int G64 = GatherCfg<64>::NPB;   // 64  nodes/block
    constexpr int G32 = GatherCfg<32>::NPB;   // 128 nodes/block
    constexpr int G16 = GatherCfg<16>::NPB;   // 256 nodes/block

    // ---- layer 1: 128 -> 64 ----
    proj_kernel<128, 64><<<(N + 15) / 16, 256, 0, stream>>>(x, W1l, nullptr, A, N);
    proj_kernel<128, 64><<<(N + 15) / 16, 256, 0, stream>>>(x, W1r, b1l, B, N);
    gather_kernel<64><<<(N + G64 - 1) / G64, 256, 0, stream>>>(A, rowptr, adj, B, N);
    // ---- layer 2: 64 -> 32 ----
    proj_kernel<64, 32><<<(N + 31) / 32, 256, 0, stream>>>(B, W2l, nullptr, A, N);
    proj_kernel<64, 32><<<(N + 31) / 32, 256, 0, stream>>>(B, W2r, b2l, C, N);
    gather_kernel<32><<<(N + G32 - 1) / G32, 256, 0, stream>>>(A, rowptr, adj, C, N);
    // ---- layer 3: 32 -> 16 ----
    proj_kernel<32, 16><<<(N + 63) / 64, 256, 0, stream>>>(C, W3l, nullptr, A, N);
    proj_kernel<32, 16><<<(N + 63) / 64, 256, 0, stream>>>(C, W3r, b3l, D, N);
    gather_kernel<16><<<(N + G16 - 1) / G16, 256, 0, stream>>>(A, rowptr, adj, D, N);

    // ---- heads ----
    k_head<<<(N + 255) / 256, 256, 0, stream>>>(D, Wreg, breg, Wcls, bcls, (float*)d_out, N);
}

// Round 4
// 1519.494 us; speedup vs baseline: 1.6758x; 1.2032x over previous
//
#include <hip/hip_runtime.h>

// ---------------------------------------------------------------------------
// BikeSafetyGNN: 3-layer GraphSAGE (mean) + 2 linear heads, fp32.
// R4: (a) bucketed CSR build — bucket=dst>>10, tile-local LDS counting sort
//     into bucket-contiguous temp T (reuses B's memory), then per-bucket fill
//     with LDS cursors so adj scatter stays L2-resident (kills the 396 MB
//     write amplification of the old k_fill).
//     (b) bf16 P-buffer: proj_l stores bf16 (RNE), gather unpacks uint2 ->
//     fp32 accumulate. Halves the dominant L3 gather traffic.
// ---------------------------------------------------------------------------

__device__ __forceinline__ void f4add(float4& a, const float4 b) {
    a.x += b.x; a.y += b.y; a.z += b.z; a.w += b.w;
}

__device__ __forceinline__ unsigned short f2bf_rne(float f) {
    unsigned int u = __float_as_uint(f);
    u = (u + 0x7FFFu + ((u >> 16) & 1u)) >> 16;
    return (unsigned short)u;
}

// unpack 4 bf16 (packed little-endian in uint2) and accumulate into float4
__device__ __forceinline__ void bfacc(float4& a, const uint2 q) {
    a.x += __uint_as_float(q.x << 16);
    a.y += __uint_as_float(q.x & 0xFFFF0000u);
    a.z += __uint_as_float(q.y << 16);
    a.w += __uint_as_float(q.y & 0xFFFF0000u);
}

__global__ __launch_bounds__(256) void k_deg(const int* __restrict__ dst, int E,
                                             int* __restrict__ deg, int N) {
    int i = blockIdx.x * 256 + threadIdx.x;
    if (i < E) {
        int d = dst[i];
        d = d < 0 ? 0 : (d >= N ? N - 1 : d);
        atomicAdd(&deg[d], 1);
    }
}

// ---- 2-level exclusive scan over deg[N] -> rowptr[N+1], chunk = 2048 ----
__global__ __launch_bounds__(256) void k_scan_partial(const int* __restrict__ deg,
                                                      int N, int* __restrict__ sums) {
    __shared__ int sd[256];
    int base = blockIdx.x * 2048 + threadIdx.x * 8;
    int s = 0;
    #pragma unroll
    for (int i = 0; i < 8; ++i) { int idx = base + i; if (idx < N) s += deg[idx]; }
    sd[threadIdx.x] = s; __syncthreads();
    for (int off = 128; off > 0; off >>= 1) {
        if (threadIdx.x < off) sd[threadIdx.x] += sd[threadIdx.x + off];
        __syncthreads();
    }
    if (threadIdx.x == 0) sums[blockIdx.x] = sd[0];
}

__global__ __launch_bounds__(256) void k_scan_offsets(int* __restrict__ sums, int NB) {
    __shared__ int sd[256];
    int tid = threadIdx.x;
    int v = (tid < NB) ? sums[tid] : 0;
    sd[tid] = v; __syncthreads();
    for (int off = 1; off < 256; off <<= 1) {
        int t = (tid >= off) ? sd[tid - off] : 0;
        __syncthreads();
        sd[tid] += t;
        __syncthreads();
    }
    if (tid < NB) sums[tid] = sd[tid] - v;   // exclusive
}

__global__ __launch_bounds__(256) void k_scan_final(const int* __restrict__ deg, int N,
                                                    const int* __restrict__ sums,
                                                    int* __restrict__ rowptr, int E) {
    __shared__ int sd[256];
    int tid = threadIdx.x;
    int base = blockIdx.x * 2048 + tid * 8;
    int v[8]; int s = 0;
    #pragma unroll
    for (int i = 0; i < 8; ++i) { int idx = base + i; v[i] = (idx < N) ? deg[idx] : 0; s += v[i]; }
    sd[tid] = s; __syncthreads();
    for (int off = 1; off < 256; off <<= 1) {
        int t = (tid >= off) ? sd[tid - off] : 0;
        __syncthreads();
        sd[tid] += t;
        __syncthreads();
    }
    int run = sums[blockIdx.x] + sd[tid] - s;  // exclusive prefix for this thread
    #pragma unroll
    for (int i = 0; i < 8; ++i) { int idx = base + i; if (idx < N) rowptr[idx] = run; run += v[i]; }
    if (blockIdx.x == 0 && tid == 0) rowptr[N] = E;
}

// ---- pass A: counting-sort edge pairs into bucket-contiguous chunks of T ----
// bucket b = dst >> 10 (contiguous node ranges => bucket offset = rowptr[b<<10])
#define BTILE 4096
__global__ __launch_bounds__(256) void k_bucket(const int* __restrict__ src,
                                                const int* __restrict__ dst, int E, int N,
                                                const int* __restrict__ rowptr,
                                                int* __restrict__ bcur,
                                                int2* __restrict__ T, int NBK) {
    __shared__ int cnt[256], cnt2[256], lofs[256], gbase[256], boffs[256], sd[256];
    __shared__ int2 staged[BTILE];
    const int tid = threadIdx.x;
    const int tb = blockIdx.x * BTILE;
    const int tn = min(BTILE, E - tb);
    cnt[tid] = 0; cnt2[tid] = 0;
    {   // bucket base offsets from rowptr
        int nodeb = tid << 10;
        boffs[tid] = rowptr[nodeb > N ? N : nodeb];
    }
    __syncthreads();
    // phase 1: count buckets in this tile
    for (int i = tid; i < tn; i += 256) {
        int d = dst[tb + i];
        d = d < 0 ? 0 : (d >= N ? N - 1 : d);
        atomicAdd(&cnt[d >> 10], 1);
    }
    __syncthreads();
    // phase 2: exclusive scan cnt -> lofs
    int v = cnt[tid];
    sd[tid] = v; __syncthreads();
    for (int off = 1; off < 256; off <<= 1) {
        int t = (tid >= off) ? sd[tid - off] : 0;
        __syncthreads();
        sd[tid] += t;
        __syncthreads();
    }
    lofs[tid] = sd[tid] - v;
    // phase 3: reserve global space per bucket
    if (v > 0 && tid < NBK) gbase[tid] = atomicAdd(&bcur[tid], v);
    __syncthreads();
    // phase 4: place pairs into LDS, bucket-sorted
    for (int i = tid; i < tn; i += 256) {
        int d = dst[tb + i];
        d = d < 0 ? 0 : (d >= N ? N - 1 : d);
        int s = src[tb + i];
        s = s < 0 ? 0 : (s >= N ? N - 1 : s);
        int b = d >> 10;
        int r = atomicAdd(&cnt2[b], 1);
        staged[lofs[b] + r] = make_int2(s, d);
    }
    __syncthreads();
    // phase 5: contiguous runs -> global T
    for (int i = tid; i < tn; i += 256) {
        int2 p = staged[i];
        int b = p.y >> 10;
        T[(size_t)boffs[b] + gbase[b] + (i - lofs[b])] = p;
    }
}

// ---- pass B: per-bucket adj fill; scatter confined to L2-resident region ----
__global__ __launch_bounds__(256) void k_bfill(const int2* __restrict__ T,
                                               const int* __restrict__ rowptr,
                                               int* __restrict__ adj, int N) {
    __shared__ int cur[1024];
    const int tid = threadIdx.x;
    const int node0 = blockIdx.x << 10;
    const int node1 = min(node0 + 1024, N);
    for (int i = tid; i < 1024; i += 256) cur[i] = 0;
    __syncthreads();
    const int beg = rowptr[node0], end = rowptr[node1];
    for (int i = beg + tid; i < end; i += 256) {
        int2 p = T[i];
        int pos = rowptr[p.y] + atomicAdd(&cur[p.y - node0], 1);
        adj[pos] = p.x;
    }
}

// ---- P = H @ W^T (+bias if non-null); optional bf16 output ----
template<int DIN, int DOUT, bool BF16OUT>
__global__ __launch_bounds__(256) void proj_kernel(const float* __restrict__ H,
                                                   const float* __restrict__ W,
                                                   const float* __restrict__ bias,
                                                   void* __restrict__ Pout, int N) {
    constexpr int SUBS = 64 / DOUT;
    constexpr int M = 4;
    constexpr int NPW = SUBS * M;
    constexpr int NPB = NPW * 4;
    __shared__ float wt[DIN * DOUT];  // [k/4][c][4]
    for (int idx = threadIdx.x; idx < DIN * DOUT; idx += 256) {
        int c = idx / DIN, k = idx % DIN;
        wt[(k >> 2) * (DOUT * 4) + c * 4 + (k & 3)] = W[idx];
    }
    __syncthreads();
    const int wave = threadIdx.x >> 6, lane = threadIdx.x & 63;
    const int c = lane % DOUT, sub = lane / DOUT;
    const int nodebase = blockIdx.x * NPB + wave * NPW + sub;
    int nm[M]; bool vm[M];
    #pragma unroll
    for (int m = 0; m < M; ++m) {
        int n = nodebase + m * SUBS;
        vm[m] = (n < N);
        nm[m] = vm[m] ? n : 0;
    }
    float acc[M] = {};
    const float4* wt4 = (const float4*)wt;
    for (int k4 = 0; k4 < DIN / 4; ++k4) {
        float4 w = wt4[k4 * DOUT + c];
        #pragma unroll
        for (int m = 0; m < M; ++m) {
            float4 h = ((const float4*)(H + (size_t)nm[m] * DIN))[k4];
            acc[m] += w.x * h.x + w.y * h.y + w.z * h.z + w.w * h.w;
        }
    }
    float bc = bias ? bias[c] : 0.0f;
    #pragma unroll
    for (int m = 0; m < M; ++m) {
        if (!vm[m]) continue;
        if (BF16OUT) {
            ((unsigned short*)Pout)[(size_t)nm[m] * DOUT + c] = f2bf_rne(acc[m] + bc);
        } else {
            ((float*)Pout)[(size_t)nm[m] * DOUT + c] = acc[m] + bc;
        }
    }
}

// nodes-per-block constants shared between kernel and launch
template<int DOUT> struct GatherCfg {
    static constexpr int L   = DOUT / 4;   // uint2s (4 bf16) per node row
    static constexpr int S   = 64 / L;     // nodes concurrently per wave
    static constexpr int M   = 4;          // sequential nodes per subgroup
    static constexpr int NPW = S * M;
    static constexpr int NPB = NPW * 4;    // 4 waves/block
};

// ---- Hout = relu( mean_{j in N(n)} P[j] + Hout[n] ), P in bf16 ----
template<int DOUT>
__global__ __launch_bounds__(256, 6) void gather_kernel(const unsigned short* __restrict__ P,
                                                        const int* __restrict__ rowptr,
                                                        const int* __restrict__ adj,
                                                        float* __restrict__ Hout, int N) {
    using C = GatherCfg<DOUT>;
    constexpr int L = C::L;
    constexpr int S = C::S;
    constexpr int M = C::M;
    constexpr int NPW = C::NPW;
    constexpr int NPB = C::NPB;
    const int wave = threadIdx.x >> 6, lane = threadIdx.x & 63;
    const int sub = lane / L, cl = lane % L;
    const uint2* __restrict__ P2 = (const uint2*)P;
    float4* __restrict__ H4 = (float4*)Hout;
    const int base = blockIdx.x * NPB + wave * NPW + sub;
    #pragma unroll 1
    for (int m = 0; m < M; ++m) {
        int n = base + m * S;
        if (n >= N) continue;
        int beg = rowptr[n], end = rowptr[n + 1];
        float4 a0 = {0, 0, 0, 0}, a1 = {0, 0, 0, 0}, a2 = {0, 0, 0, 0}, a3 = {0, 0, 0, 0};
        int j = beg;
        while (j < end && (j & 3)) { bfacc(a0, P2[(size_t)adj[j] * L + cl]); ++j; }
        for (; j + 8 <= end; j += 8) {
            int4 sA = *(const int4*)(adj + j);
            int4 sB = *(const int4*)(adj + j + 4);
            uint2 p0 = P2[(size_t)sA.x * L + cl];
            uint2 p1 = P2[(size_t)sA.y * L + cl];
            uint2 p2 = P2[(size_t)sA.z * L + cl];
            uint2 p3 = P2[(size_t)sA.w * L + cl];
            uint2 p4 = P2[(size_t)sB.x * L + cl];
            uint2 p5 = P2[(size_t)sB.y * L + cl];
            uint2 p6 = P2[(size_t)sB.z * L + cl];
            uint2 p7 = P2[(size_t)sB.w * L + cl];
            bfacc(a0, p0); bfacc(a1, p1); bfacc(a2, p2); bfacc(a3, p3);
            bfacc(a0, p4); bfacc(a1, p5); bfacc(a2, p6); bfacc(a3, p7);
        }
        if (j + 4 <= end) {
            int4 sA = *(const int4*)(adj + j);
            bfacc(a0, P2[(size_t)sA.x * L + cl]);
            bfacc(a1, P2[(size_t)sA.y * L + cl]);
            bfacc(a2, P2[(size_t)sA.z * L + cl]);
            bfacc(a3, P2[(size_t)sA.w * L + cl]);
            j += 4;
        }
        for (; j < end; ++j) bfacc(a0, P2[(size_t)adj[j] * L + cl]);
        int deg = end - beg;
        float inv = deg > 0 ? 1.0f / (float)deg : 0.0f;
        float4 r = H4[(size_t)n * L + cl];
        float4 o;
        o.x = fmaxf((a0.x + a1.x + a2.x + a3.x) * inv + r.x, 0.0f);
        o.y = fmaxf((a0.y + a1.y + a2.y + a3.y) * inv + r.y, 0.0f);
        o.z = fmaxf((a0.z + a1.z + a2.z + a3.z) * inv + r.z, 0.0f);
        o.w = fmaxf((a0.w + a1.w + a2.w + a3.w) * inv + r.w, 0.0f);
        H4[(size_t)n * L + cl] = o;
    }
}

__global__ __launch_bounds__(256) void k_head(const float* __restrict__ H3,
                                              const float* __restrict__ Wreg,
                                              const float* __restrict__ breg,
                                              const float* __restrict__ Wcls,
                                              const float* __restrict__ bcls,
                                              float* __restrict__ out, int N) {
    int i = blockIdx.x * 256 + threadIdx.x;
    if (i >= N) return;
    const float4* h = (const float4*)(H3 + (size_t)i * 16);
    float reg = 0.f, cls = 0.f;
    #pragma unroll
    for (int k4 = 0; k4 < 4; ++k4) {
        float4 hv = h[k4];
        float4 wr = ((const float4*)Wreg)[k4];
        float4 wc = ((const float4*)Wcls)[k4];
        reg += hv.x * wr.x + hv.y * wr.y + hv.z * wr.z + hv.w * wr.w;
        cls += hv.x * wc.x + hv.y * wc.y + hv.z * wc.z + hv.w * wc.w;
    }
    out[i] = reg + breg[0];
    out[(size_t)N + i] = cls + bcls[0];
}

extern "C" void kernel_launch(void* const* d_in, const int* in_sizes, int n_in,
                              void* d_out, int out_size, void* d_ws, size_t ws_size,
                              hipStream_t stream) {
    const float* x    = (const float*)d_in[0];
    const int*   ei   = (const int*)d_in[1];
    const float* W1l  = (const float*)d_in[2];
    const float* b1l  = (const float*)d_in[3];
    const float* W1r  = (const float*)d_in[4];
    const float* W2l  = (const float*)d_in[5];
    const float* b2l  = (const float*)d_in[6];
    const float* W2r  = (const float*)d_in[7];
    const float* W3l  = (const float*)d_in[8];
    const float* b3l  = (const float*)d_in[9];
    const float* W3r  = (const float*)d_in[10];
    const float* Wreg = (const float*)d_in[11];
    const float* breg = (const float*)d_in[12];
    const float* Wcls = (const float*)d_in[13];
    const float* bcls = (const float*)d_in[14];

    const int N = in_sizes[0] / 128;
    const int E = in_sizes[1] / 2;
    const int* src = ei;
    const int* dst = ei + E;

    char* ws = (char*)d_ws;
    size_t off = 0;
    auto alloc = [&](size_t bytes) -> void* {
        void* p = ws + off;
        off += (bytes + 255) & ~(size_t)255;
        return p;
    };
    int*   rowptr = (int*)alloc((size_t)(N + 1) * 4);
    int*   deg    = (int*)alloc((size_t)N * 4);
    int*   sums   = (int*)alloc(1024);
    int*   bcur   = (int*)alloc(1024);
    int*   adj    = (int*)alloc((size_t)E * 4);
    unsigned short* A = (unsigned short*)alloc((size_t)N * 64 * 2);  // bf16 P
    float* B      = (float*)alloc((size_t)N * 64 * 4);  // h1; doubles as T during CSR build
    float* C      = (float*)alloc((size_t)N * 32 * 4);  // h2
    float* D      = (float*)alloc((size_t)N * 16 * 4);  // h3
    int2*  T      = (int2*)B;                            // E*8B == N*64*4B exactly

    const int gE = (E + 255) / 256;
    const int NB = (N + 2047) / 2048;     // level-2 scan blocks (98)
    const int NBK = (N + 1023) >> 10;     // buckets (196)

    // ---- CSR build ----
    hipMemsetAsync(deg, 0, (size_t)N * 4, stream);
    hipMemsetAsync(bcur, 0, 1024, stream);
    k_deg<<<gE, 256, 0, stream>>>(dst, E, deg, N);
    k_scan_partial<<<NB, 256, 0, stream>>>(deg, N, sums);
    k_scan_offsets<<<1, 256, 0, stream>>>(sums, NB);
    k_scan_final<<<NB, 256, 0, stream>>>(deg, N, sums, rowptr, E);
    k_bucket<<<(E + BTILE - 1) / BTILE, 256, 0, stream>>>(src, dst, E, N, rowptr, bcur, T, NBK);
    k_bfill<<<NBK, 256, 0, stream>>>(T, rowptr, adj, N);

    constexpr int G64 = GatherCfg<64>::NPB;
    constexpr int G32 = GatherCfg<32>::NPB;
    constexpr int G16 = GatherCfg<16>::NPB;

    // ---- layer 1: 128 -> 64 ----
    proj_kernel<128, 64, true ><<<(N + 15) / 16, 256, 0, stream>>>(x, W1l, nullptr, A, N);
    proj_kernel<128, 64, false><<<(N + 15) / 16, 256, 0, stream>>>(x, W1r, b1l, B, N);
    gather_kernel<64><<<(N + G64 - 1) / G64, 256, 0, stream>>>(A, rowptr, adj, B, N);
    // ---- layer 2: 64 -> 32 ----
    proj_kernel<64, 32, true ><<<(N + 31) / 32, 256, 0, stream>>>(B, W2l, nullptr, A, N);
    proj_kernel<64, 32, false><<<(N + 31) / 32, 256, 0, stream>>>(B, W2r, b2l, C, N);
    gather_kernel<32><<<(N + G32 - 1) / G32, 256, 0, stream>>>(A, rowptr, adj, C, N);
    // ---- layer 3: 32 -> 16 ----
    proj_kernel<32, 16, true ><<<(N + 63) / 64, 256, 0, stream>>>(C, W3l, nullptr, A, N);
    proj_kernel<32, 16, false><<<(N + 63) / 64, 256, 0, stream>>>(C, W3r, b3l, D, N);
    gather_kernel<16><<<(N + G16 - 1) / G16, 256, 0, stream>>>(A, rowptr, adj, D, N);

    // ---- heads ----
    k_head<<<(N + 255) / 256, 256, 0, stream>>>(D, Wreg, breg, Wcls, bcls, (float*)d_out, N);
}

// Round 5
// 887.337 us; speedup vs baseline: 2.8698x; 1.7124x over previous
//
#include <hip/hip_runtime.h>

// ---------------------------------------------------------------------------
// BikeSafetyGNN: 3-layer GraphSAGE (mean) + 2 linear heads, fp32.
// R5: (a) atomic-free CSR: bucket-count -> bucket-scan -> tile-sort into T ->
//         per-bucket LDS degree histogram + block scan writes rowptr directly
//         (k_deg and its 200 MB of atomic write amplification deleted).
//     (b) fused Wl+Wr projection, 4 output channels per lane, LDS weight
//         layout [(k4*4+j)*LPN+cl] (2-way bank aliasing = free). Pl bf16
//         ushort4 stores, R float4 stores.
// ---------------------------------------------------------------------------

__device__ __forceinline__ unsigned short f2bf_rne(float f) {
    unsigned int u = __float_as_uint(f);
    u = (u + 0x7FFFu + ((u >> 16) & 1u)) >> 16;
    return (unsigned short)u;
}

// unpack 4 bf16 (packed little-endian in uint2) and accumulate into float4
__device__ __forceinline__ void bfacc(float4& a, const uint2 q) {
    a.x += __uint_as_float(q.x << 16);
    a.y += __uint_as_float(q.x & 0xFFFF0000u);
    a.z += __uint_as_float(q.y << 16);
    a.w += __uint_as_float(q.y & 0xFFFF0000u);
}

// ---------------- CSR build (bucket = dst >> 10) ----------------

__global__ __launch_bounds__(256) void k_bcount(const int* __restrict__ dst, int E, int N,
                                                int* __restrict__ bcnt) {
    __shared__ int h[256];
    const int tid = threadIdx.x;
    h[tid] = 0;
    __syncthreads();
    const int stride = gridDim.x * 256;
    for (int i = blockIdx.x * 256 + tid; i < E; i += stride) {
        int d = dst[i];
        d = d < 0 ? 0 : (d >= N ? N - 1 : d);
        atomicAdd(&h[d >> 10], 1);
    }
    __syncthreads();
    if (h[tid]) atomicAdd(&bcnt[tid], h[tid]);
}

__global__ __launch_bounds__(256) void k_bscan(const int* __restrict__ bcnt,
                                               int* __restrict__ boff, int NBK, int E) {
    __shared__ int sd[256];
    const int tid = threadIdx.x;
    int v = (tid < NBK) ? bcnt[tid] : 0;
    sd[tid] = v; __syncthreads();
    for (int off = 1; off < 256; off <<= 1) {
        int t = (tid >= off) ? sd[tid - off] : 0;
        __syncthreads();
        sd[tid] += t;
        __syncthreads();
    }
    if (tid < NBK) boff[tid] = sd[tid] - v;   // exclusive
    if (tid == 0) boff[NBK] = E;
}

// tile-local LDS counting sort of (src,dst) pairs into bucket-contiguous T
#define BTILE 4096
__global__ __launch_bounds__(256) void k_bucket(const int* __restrict__ src,
                                                const int* __restrict__ dst, int E, int N,
                                                const int* __restrict__ boff,
                                                int* __restrict__ bcur,
                                                int2* __restrict__ T, int NBK) {
    __shared__ int cnt[256], cnt2[256], lofs[256], gbase[256], boffs[256], sd[256];
    __shared__ int2 staged[BTILE];
    const int tid = threadIdx.x;
    const int tb = blockIdx.x * BTILE;
    const int tn = min(BTILE, E - tb);
    cnt[tid] = 0; cnt2[tid] = 0;
    boffs[tid] = (tid < NBK) ? boff[tid] : 0;
    __syncthreads();
    for (int i = tid; i < tn; i += 256) {
        int d = dst[tb + i];
        d = d < 0 ? 0 : (d >= N ? N - 1 : d);
        atomicAdd(&cnt[d >> 10], 1);
    }
    __syncthreads();
    int v = cnt[tid];
    sd[tid] = v; __syncthreads();
    for (int off = 1; off < 256; off <<= 1) {
        int t = (tid >= off) ? sd[tid - off] : 0;
        __syncthreads();
        sd[tid] += t;
        __syncthreads();
    }
    lofs[tid] = sd[tid] - v;
    if (v > 0 && tid < NBK) gbase[tid] = atomicAdd(&bcur[tid], v);
    __syncthreads();
    for (int i = tid; i < tn; i += 256) {
        int d = dst[tb + i];
        d = d < 0 ? 0 : (d >= N ? N - 1 : d);
        int s = src[tb + i];
        s = s < 0 ? 0 : (s >= N ? N - 1 : s);
        int b = d >> 10;
        int r = atomicAdd(&cnt2[b], 1);
        staged[lofs[b] + r] = make_int2(s, d);
    }
    __syncthreads();
    for (int i = tid; i < tn; i += 256) {
        int2 p = staged[i];
        int b = p.y >> 10;
        T[(size_t)boffs[b] + gbase[b] + (i - lofs[b])] = p;
    }
}

// per bucket: LDS degree histogram + block scan -> rowptr (no global scan)
__global__ __launch_bounds__(256) void k_brow(const int2* __restrict__ T,
                                              const int* __restrict__ boff,
                                              int* __restrict__ rowptr, int N, int E) {
    __shared__ int ldeg[1024];
    __shared__ int sd[256];
    const int tid = threadIdx.x;
    const int b = blockIdx.x;
    const int node0 = b << 10;
    #pragma unroll
    for (int i = 0; i < 4; ++i) ldeg[tid * 4 + i] = 0;
    __syncthreads();
    const int beg = boff[b], end = boff[b + 1];
    for (int i = beg + tid; i < end; i += 256)
        atomicAdd(&ldeg[T[i].y - node0], 1);
    __syncthreads();
    int v0 = ldeg[tid * 4], v1 = ldeg[tid * 4 + 1], v2 = ldeg[tid * 4 + 2], v3 = ldeg[tid * 4 + 3];
    int s = v0 + v1 + v2 + v3;
    sd[tid] = s; __syncthreads();
    for (int off = 1; off < 256; off <<= 1) {
        int t = (tid >= off) ? sd[tid - off] : 0;
        __syncthreads();
        sd[tid] += t;
        __syncthreads();
    }
    int run = beg + sd[tid] - s;   // exclusive prefix for this thread's 4 nodes
    int n = node0 + tid * 4;
    if (n     < N) rowptr[n]     = run;            run += v0;
    if (n + 1 < N) rowptr[n + 1] = run;            run += v1;
    if (n + 2 < N) rowptr[n + 2] = run;            run += v2;
    if (n + 3 < N) rowptr[n + 3] = run;
    if (tid == 0 && b == 0) rowptr[N] = E;
}

// per-bucket adj fill; scatter confined to L2-resident region
__global__ __launch_bounds__(256) void k_bfill(const int2* __restrict__ T,
                                               const int* __restrict__ boff,
                                               const int* __restrict__ rowptr,
                                               int* __restrict__ adj, int N) {
    __shared__ int cur[1024];
    const int tid = threadIdx.x;
    const int b = blockIdx.x;
    const int node0 = b << 10;
    for (int i = tid; i < 1024; i += 256) cur[i] = 0;
    __syncthreads();
    const int beg = boff[b], end = boff[b + 1];
    for (int i = beg + tid; i < end; i += 256) {
        int2 p = T[i];
        int pos = rowptr[p.y] + atomicAdd(&cur[p.y - node0], 1);
        adj[pos] = p.x;
    }
}

// ---------------- fused projection: Pl = H@Wl^T (bf16), R = H@Wr^T + b ----------------

template<int DIN, int DOUT> struct ProjCfg {
    static constexpr int CPL = 4;            // output channels per lane
    static constexpr int LPN = DOUT / CPL;   // lanes per node
    static constexpr int SUBS = 64 / LPN;    // nodes concurrently per wave
    static constexpr int M = 4;              // sequential nodes per subgroup
    static constexpr int NPW = SUBS * M;
    static constexpr int NPB = NPW * 4;      // 4 waves/block
};

template<int DIN, int DOUT>
__global__ __launch_bounds__(256) void proj2_kernel(const float* __restrict__ H,
                                                    const float* __restrict__ Wl,
                                                    const float* __restrict__ Wr,
                                                    const float* __restrict__ bias,
                                                    unsigned short* __restrict__ Pl,
                                                    float* __restrict__ R, int N) {
    using C = ProjCfg<DIN, DOUT>;
    constexpr int CPL = C::CPL, LPN = C::LPN, SUBS = C::SUBS, M = C::M;
    constexpr int NPW = C::NPW, NPB = C::NPB;
    // LDS weights: wt[(k4*CPL + j)*LPN + cl] (float4) = W[c=cl*CPL+j][4k4..4k4+3]
    __shared__ float wtl[DIN * DOUT];
    __shared__ float wtr[DIN * DOUT];
    for (int idx = threadIdx.x; idx < DIN * DOUT; idx += 256) {
        int c = idx / DIN, k = idx % DIN;
        int cl = c / CPL, j = c % CPL;
        int dstf = (((k >> 2) * CPL + j) * LPN + cl) * 4 + (k & 3);
        wtl[dstf] = Wl[idx];
        wtr[dstf] = Wr[idx];
    }
    __syncthreads();
    const int wave = threadIdx.x >> 6, lane = threadIdx.x & 63;
    const int cl = lane % LPN, sub = lane / LPN;
    const int nodebase = blockIdx.x * NPB + wave * NPW + sub;
    int nm[M]; bool vm[M];
    #pragma unroll
    for (int m = 0; m < M; ++m) {
        int n = nodebase + m * SUBS;
        vm[m] = (n < N);
        nm[m] = vm[m] ? n : 0;
    }
    float accl[M][CPL] = {};
    float accr[M][CPL] = {};
    const float4* wtl4 = (const float4*)wtl;
    const float4* wtr4 = (const float4*)wtr;
    for (int k4 = 0; k4 < DIN / 4; ++k4) {
        float4 wl[CPL], wr[CPL];
        #pragma unroll
        for (int j = 0; j < CPL; ++j) {
            wl[j] = wtl4[(k4 * CPL + j) * LPN + cl];
            wr[j] = wtr4[(k4 * CPL + j) * LPN + cl];
        }
        #pragma unroll
        for (int m = 0; m < M; ++m) {
            float4 h = ((const float4*)(H + (size_t)nm[m] * DIN))[k4];
            #pragma unroll
            for (int j = 0; j < CPL; ++j) {
                accl[m][j] += wl[j].x * h.x + wl[j].y * h.y + wl[j].z * h.z + wl[j].w * h.w;
                accr[m][j] += wr[j].x * h.x + wr[j].y * h.y + wr[j].z * h.z + wr[j].w * h.w;
            }
        }
    }
    float4 b4 = ((const float4*)bias)[cl];
    #pragma unroll
    for (int m = 0; m < M; ++m) {
        if (!vm[m]) continue;
        ushort4 pk;
        pk.x = f2bf_rne(accl[m][0]);
        pk.y = f2bf_rne(accl[m][1]);
        pk.z = f2bf_rne(accl[m][2]);
        pk.w = f2bf_rne(accl[m][3]);
        *(ushort4*)(Pl + (size_t)nm[m] * DOUT + cl * 4) = pk;
        float4 rv;
        rv.x = accr[m][0] + b4.x;
        rv.y = accr[m][1] + b4.y;
        rv.z = accr[m][2] + b4.z;
        rv.w = accr[m][3] + b4.w;
        *(float4*)(R + (size_t)nm[m] * DOUT + cl * 4) = rv;
    }
}

// ---------------- gather: Hout = relu( mean P[j] + Hout ), P bf16 ----------------

template<int DOUT> struct GatherCfg {
    static constexpr int L   = DOUT / 4;   // uint2s (4 bf16) per node row
    static constexpr int S   = 64 / L;     // nodes concurrently per wave
    static constexpr int M   = 4;          // sequential nodes per subgroup
    static constexpr int NPW = S * M;
    static constexpr int NPB = NPW * 4;    // 4 waves/block
};

template<int DOUT>
__global__ __launch_bounds__(256, 6) void gather_kernel(const unsigned short* __restrict__ P,
                                                        const int* __restrict__ rowptr,
                                                        const int* __restrict__ adj,
                                                        float* __restrict__ Hout, int N) {
    using C = GatherCfg<DOUT>;
    constexpr int L = C::L, S = C::S, M = C::M;
    constexpr int NPW = C::NPW, NPB = C::NPB;
    const int wave = threadIdx.x >> 6, lane = threadIdx.x & 63;
    const int sub = lane / L, cl = lane % L;
    const uint2* __restrict__ P2 = (const uint2*)P;
    float4* __restrict__ H4 = (float4*)Hout;
    const int base = blockIdx.x * NPB + wave * NPW + sub;
    #pragma unroll 1
    for (int m = 0; m < M; ++m) {
        int n = base + m * S;
        if (n >= N) continue;
        int beg = rowptr[n], end = rowptr[n + 1];
        float4 a0 = {0, 0, 0, 0}, a1 = {0, 0, 0, 0}, a2 = {0, 0, 0, 0}, a3 = {0, 0, 0, 0};
        int j = beg;
        while (j < end && (j & 3)) { bfacc(a0, P2[(size_t)adj[j] * L + cl]); ++j; }
        for (; j + 8 <= end; j += 8) {
            int4 sA = *(const int4*)(adj + j);
            int4 sB = *(const int4*)(adj + j + 4);
            uint2 p0 = P2[(size_t)sA.x * L + cl];
            uint2 p1 = P2[(size_t)sA.y * L + cl];
            uint2 p2 = P2[(size_t)sA.z * L + cl];
            uint2 p3 = P2[(size_t)sA.w * L + cl];
            uint2 p4 = P2[(size_t)sB.x * L + cl];
            uint2 p5 = P2[(size_t)sB.y * L + cl];
            uint2 p6 = P2[(size_t)sB.z * L + cl];
            uint2 p7 = P2[(size_t)sB.w * L + cl];
            bfacc(a0, p0); bfacc(a1, p1); bfacc(a2, p2); bfacc(a3, p3);
            bfacc(a0, p4); bfacc(a1, p5); bfacc(a2, p6); bfacc(a3, p7);
        }
        if (j + 4 <= end) {
            int4 sA = *(const int4*)(adj + j);
            bfacc(a0, P2[(size_t)sA.x * L + cl]);
            bfacc(a1, P2[(size_t)sA.y * L + cl]);
            bfacc(a2, P2[(size_t)sA.z * L + cl]);
            bfacc(a3, P2[(size_t)sA.w * L + cl]);
            j += 4;
        }
        for (; j < end; ++j) bfacc(a0, P2[(size_t)adj[j] * L + cl]);
        int deg = end - beg;
        float inv = deg > 0 ? 1.0f / (float)deg : 0.0f;
        float4 r = H4[(size_t)n * L + cl];
        float4 o;
        o.x = fmaxf((a0.x + a1.x + a2.x + a3.x) * inv + r.x, 0.0f);
        o.y = fmaxf((a0.y + a1.y + a2.y + a3.y) * inv + r.y, 0.0f);
        o.z = fmaxf((a0.z + a1.z + a2.z + a3.z) * inv + r.z, 0.0f);
        o.w = fmaxf((a0.w + a1.w + a2.w + a3.w) * inv + r.w, 0.0f);
        H4[(size_t)n * L + cl] = o;
    }
}

__global__ __launch_bounds__(256) void k_head(const float* __restrict__ H3,
                                              const float* __restrict__ Wreg,
                                              const float* __restrict__ breg,
                                              const float* __restrict__ Wcls,
                                              const float* __restrict__ bcls,
                                              float* __restrict__ out, int N) {
    int i = blockIdx.x * 256 + threadIdx.x;
    if (i >= N) return;
    const float4* h = (const float4*)(H3 + (size_t)i * 16);
    float reg = 0.f, cls = 0.f;
    #pragma unroll
    for (int k4 = 0; k4 < 4; ++k4) {
        float4 hv = h[k4];
        float4 wr = ((const float4*)Wreg)[k4];
        float4 wc = ((const float4*)Wcls)[k4];
        reg += hv.x * wr.x + hv.y * wr.y + hv.z * wr.z + hv.w * wr.w;
        cls += hv.x * wc.x + hv.y * wc.y + hv.z * wc.z + hv.w * wc.w;
    }
    out[i] = reg + breg[0];
    out[(size_t)N + i] = cls + bcls[0];
}

extern "C" void kernel_launch(void* const* d_in, const int* in_sizes, int n_in,
                              void* d_out, int out_size, void* d_ws, size_t ws_size,
                              hipStream_t stream) {
    const float* x    = (const float*)d_in[0];
    const int*   ei   = (const int*)d_in[1];
    const float* W1l  = (const float*)d_in[2];
    const float* b1l  = (const float*)d_in[3];
    const float* W1r  = (const float*)d_in[4];
    const float* W2l  = (const float*)d_in[5];
    const float* b2l  = (const float*)d_in[6];
    const float* W2r  = (const float*)d_in[7];
    const float* W3l  = (const float*)d_in[8];
    const float* b3l  = (const float*)d_in[9];
    const float* W3r  = (const float*)d_in[10];
    const float* Wreg = (const float*)d_in[11];
    const float* breg = (const float*)d_in[12];
    const float* Wcls = (const float*)d_in[13];
    const float* bcls = (const float*)d_in[14];

    const int N = in_sizes[0] / 128;
    const int E = in_sizes[1] / 2;
    const int* src = ei;
    const int* dst = ei + E;

    char* ws = (char*)d_ws;
    size_t off = 0;
    auto alloc = [&](size_t bytes) -> void* {
        void* p = ws + off;
        off += (bytes + 255) & ~(size_t)255;
        return p;
    };
    int*   rowptr = (int*)alloc((size_t)(N + 1) * 4);
    int*   bcnt   = (int*)alloc(1024);
    int*   bcur   = (int*)alloc(1024);
    int*   boff   = (int*)alloc(1028);
    int*   adj    = (int*)alloc((size_t)E * 4);
    unsigned short* A = (unsigned short*)alloc((size_t)N * 64 * 2);  // bf16 P
    float* B      = (float*)alloc((size_t)N * 64 * 4);  // h1; doubles as T during CSR build
    float* C      = (float*)alloc((size_t)N * 32 * 4);  // h2
    float* D      = (float*)alloc((size_t)N * 16 * 4);  // h3
    int2*  T      = (int2*)B;                            // E*8B == N*64*4B exactly

    const int NBK = (N + 1023) >> 10;     // buckets (196; must be <= 256)

    // ---- CSR build (atomic-amplification-free) ----
    hipMemsetAsync(bcnt, 0, 1024, stream);
    hipMemsetAsync(bcur, 0, 1024, stream);
    k_bcount<<<1024, 256, 0, stream>>>(dst, E, N, bcnt);
    k_bscan<<<1, 256, 0, stream>>>(bcnt, boff, NBK, E);
    k_bucket<<<(E + BTILE - 1) / BTILE, 256, 0, stream>>>(src, dst, E, N, boff, bcur, T, NBK);
    k_brow<<<NBK, 256, 0, stream>>>(T, boff, rowptr, N, E);
    k_bfill<<<NBK, 256, 0, stream>>>(T, boff, rowptr, adj, N);

    constexpr int P1 = ProjCfg<128, 64>::NPB;
    constexpr int P2 = ProjCfg<64, 32>::NPB;
    constexpr int P3 = ProjCfg<32, 16>::NPB;
    constexpr int G64 = GatherCfg<64>::NPB;
    constexpr int G32 = GatherCfg<32>::NPB;
    constexpr int G16 = GatherCfg<16>::NPB;

    // ---- layer 1: 128 -> 64 ----
    proj2_kernel<128, 64><<<(N + P1 - 1) / P1, 256, 0, stream>>>(x, W1l, W1r, b1l, A, B, N);
    gather_kernel<64><<<(N + G64 - 1) / G64, 256, 0, stream>>>(A, rowptr, adj, B, N);
    // ---- layer 2: 64 -> 32 ----
    proj2_kernel<64, 32><<<(N + P2 - 1) / P2, 256, 0, stream>>>(B, W2l, W2r, b2l, A, C, N);
    gather_kernel<32><<<(N + G32 - 1) / G32, 256, 0, stream>>>(A, rowptr, adj, C, N);
    // ---- layer 3: 32 -> 16 ----
    proj2_kernel<32, 16><<<(N + P3 - 1) / P3, 256, 0, stream>>>(C, W3l, W3r, b3l, A, D, N);
    gather_kernel<16><<<(N + G16 - 1) / G16, 256, 0, stream>>>(A, rowptr, adj, D, N);

    // ---- heads ----
    k_head<<<(N + 255) / 256, 256, 0, stream>>>(D, Wreg, breg, Wcls, bcls, (float*)d_out, N);
}

// Round 6
// 787.368 us; speedup vs baseline: 3.2341x; 1.1270x over previous
//
#include <hip/hip_runtime.h>

// ---------------------------------------------------------------------------
// BikeSafetyGNN: 3-layer GraphSAGE (mean) + 2 linear heads, fp32.
// R6: projections moved to bf16 MFMA (16x16x32):
//   Pl = bf16( bf16(H) @ bf16(Wl)^T )                  (mean path; avg kills err)
//   R  = hi@Wrh + hi@Wrl + lo@Wrh + b  (split-bf16 => fp32-class accuracy)
// Weights staged in LDS bf16, row stride DIN+8 (2-way bank alias = free).
// CSR build + bf16 gather unchanged from R5.
// ---------------------------------------------------------------------------

typedef __bf16 bf16x8 __attribute__((ext_vector_type(8)));
typedef float  f32x4  __attribute__((ext_vector_type(4)));

__device__ __forceinline__ unsigned short f2bf_rne(float f) {
    unsigned int u = __float_as_uint(f);
    u = (u + 0x7FFFu + ((u >> 16) & 1u)) >> 16;
    return (unsigned short)u;
}

// unpack 4 bf16 (packed little-endian in uint2) and accumulate into float4
__device__ __forceinline__ void bfacc(float4& a, const uint2 q) {
    a.x += __uint_as_float(q.x << 16);
    a.y += __uint_as_float(q.x & 0xFFFF0000u);
    a.z += __uint_as_float(q.y << 16);
    a.w += __uint_as_float(q.y & 0xFFFF0000u);
}

// ---------------- CSR build (bucket = dst >> 10) ----------------

__global__ __launch_bounds__(256) void k_bcount(const int* __restrict__ dst, int E, int N,
                                                int* __restrict__ bcnt) {
    __shared__ int h[256];
    const int tid = threadIdx.x;
    h[tid] = 0;
    __syncthreads();
    const int stride = gridDim.x * 256;
    for (int i = blockIdx.x * 256 + tid; i < E; i += stride) {
        int d = dst[i];
        d = d < 0 ? 0 : (d >= N ? N - 1 : d);
        atomicAdd(&h[d >> 10], 1);
    }
    __syncthreads();
    if (h[tid]) atomicAdd(&bcnt[tid], h[tid]);
}

__global__ __launch_bounds__(256) void k_bscan(const int* __restrict__ bcnt,
                                               int* __restrict__ boff, int NBK, int E) {
    __shared__ int sd[256];
    const int tid = threadIdx.x;
    int v = (tid < NBK) ? bcnt[tid] : 0;
    sd[tid] = v; __syncthreads();
    for (int off = 1; off < 256; off <<= 1) {
        int t = (tid >= off) ? sd[tid - off] : 0;
        __syncthreads();
        sd[tid] += t;
        __syncthreads();
    }
    if (tid < NBK) boff[tid] = sd[tid] - v;   // exclusive
    if (tid == 0) boff[NBK] = E;
}

// tile-local LDS counting sort of (src,dst) pairs into bucket-contiguous T
#define BTILE 4096
__global__ __launch_bounds__(256) void k_bucket(const int* __restrict__ src,
                                                const int* __restrict__ dst, int E, int N,
                                                const int* __restrict__ boff,
                                                int* __restrict__ bcur,
                                                int2* __restrict__ T, int NBK) {
    __shared__ int cnt[256], cnt2[256], lofs[256], gbase[256], boffs[256], sd[256];
    __shared__ int2 staged[BTILE];
    const int tid = threadIdx.x;
    const int tb = blockIdx.x * BTILE;
    const int tn = min(BTILE, E - tb);
    cnt[tid] = 0; cnt2[tid] = 0;
    boffs[tid] = (tid < NBK) ? boff[tid] : 0;
    __syncthreads();
    for (int i = tid; i < tn; i += 256) {
        int d = dst[tb + i];
        d = d < 0 ? 0 : (d >= N ? N - 1 : d);
        atomicAdd(&cnt[d >> 10], 1);
    }
    __syncthreads();
    int v = cnt[tid];
    sd[tid] = v; __syncthreads();
    for (int off = 1; off < 256; off <<= 1) {
        int t = (tid >= off) ? sd[tid - off] : 0;
        __syncthreads();
        sd[tid] += t;
        __syncthreads();
    }
    lofs[tid] = sd[tid] - v;
    if (v > 0 && tid < NBK) gbase[tid] = atomicAdd(&bcur[tid], v);
    __syncthreads();
    for (int i = tid; i < tn; i += 256) {
        int d = dst[tb + i];
        d = d < 0 ? 0 : (d >= N ? N - 1 : d);
        int s = src[tb + i];
        s = s < 0 ? 0 : (s >= N ? N - 1 : s);
        int b = d >> 10;
        int r = atomicAdd(&cnt2[b], 1);
        staged[lofs[b] + r] = make_int2(s, d);
    }
    __syncthreads();
    for (int i = tid; i < tn; i += 256) {
        int2 p = staged[i];
        int b = p.y >> 10;
        T[(size_t)boffs[b] + gbase[b] + (i - lofs[b])] = p;
    }
}

// per bucket: LDS degree histogram + block scan -> rowptr (no global scan)
__global__ __launch_bounds__(256) void k_brow(const int2* __restrict__ T,
                                              const int* __restrict__ boff,
                                              int* __restrict__ rowptr, int N, int E) {
    __shared__ int ldeg[1024];
    __shared__ int sd[256];
    const int tid = threadIdx.x;
    const int b = blockIdx.x;
    const int node0 = b << 10;
    #pragma unroll
    for (int i = 0; i < 4; ++i) ldeg[tid * 4 + i] = 0;
    __syncthreads();
    const int beg = boff[b], end = boff[b + 1];
    for (int i = beg + tid; i < end; i += 256)
        atomicAdd(&ldeg[T[i].y - node0], 1);
    __syncthreads();
    int v0 = ldeg[tid * 4], v1 = ldeg[tid * 4 + 1], v2 = ldeg[tid * 4 + 2], v3 = ldeg[tid * 4 + 3];
    int s = v0 + v1 + v2 + v3;
    sd[tid] = s; __syncthreads();
    for (int off = 1; off < 256; off <<= 1) {
        int t = (tid >= off) ? sd[tid - off] : 0;
        __syncthreads();
        sd[tid] += t;
        __syncthreads();
    }
    int run = beg + sd[tid] - s;   // exclusive prefix for this thread's 4 nodes
    int n = node0 + tid * 4;
    if (n     < N) rowptr[n]     = run;            run += v0;
    if (n + 1 < N) rowptr[n + 1] = run;            run += v1;
    if (n + 2 < N) rowptr[n + 2] = run;            run += v2;
    if (n + 3 < N) rowptr[n + 3] = run;
    if (tid == 0 && b == 0) rowptr[N] = E;
}

// per-bucket adj fill; scatter confined to L2-resident region
__global__ __launch_bounds__(256) void k_bfill(const int2* __restrict__ T,
                                               const int* __restrict__ boff,
                                               const int* __restrict__ rowptr,
                                               int* __restrict__ adj, int N) {
    __shared__ int cur[1024];
    const int tid = threadIdx.x;
    const int b = blockIdx.x;
    const int node0 = b << 10;
    for (int i = tid; i < 1024; i += 256) cur[i] = 0;
    __syncthreads();
    const int beg = boff[b], end = boff[b + 1];
    for (int i = beg + tid; i < end; i += 256) {
        int2 p = T[i];
        int pos = rowptr[p.y] + atomicAdd(&cur[p.y - node0], 1);
        adj[pos] = p.x;
    }
}

// ---------------- MFMA fused projection ----------------
// Pl = bf16(hi(H) @ bf16(Wl)^T);  R = hi@Wrh + hi@Wrl + lo@Wrh + bias
// One wave = 16 nodes x DOUT cols. 4 waves/block = 64 nodes/block.
template<int DIN, int DOUT>
__global__ __launch_bounds__(256) void proj_mfma(const float* __restrict__ H,
                                                 const float* __restrict__ Wl,
                                                 const float* __restrict__ Wr,
                                                 const float* __restrict__ bias,
                                                 unsigned short* __restrict__ Pl,
                                                 float* __restrict__ R, int N) {
    constexpr int SP = DIN + 8;       // padded LDS row stride (bf16 elems); SP*2 % 16 == 0
    constexpr int COLT = DOUT / 16;   // 16-col tiles
    __shared__ __bf16 lwl[DOUT * SP];
    __shared__ __bf16 lwrh[DOUT * SP];
    __shared__ __bf16 lwrl[DOUT * SP];
    for (int idx = threadIdx.x; idx < DIN * DOUT; idx += 256) {
        int c = idx / DIN, k = idx % DIN;
        float wl = Wl[idx], wr = Wr[idx];
        __bf16 wrh = (__bf16)wr;
        lwl[c * SP + k] = (__bf16)wl;
        lwrh[c * SP + k] = wrh;
        lwrl[c * SP + k] = (__bf16)(wr - (float)wrh);
    }
    __syncthreads();
    const int wave = threadIdx.x >> 6, lane = threadIdx.x & 63;
    const int quad = lane >> 4, l16 = lane & 15;
    const int n0 = (blockIdx.x * 4 + wave) * 16;
    int arow = n0 + l16;                       // A-frag row this lane loads
    if (arow >= N) arow = N - 1;               // clamp (N%64==0 in practice)
    const float* hrow = H + (size_t)arow * DIN;

    f32x4 zero = {0.f, 0.f, 0.f, 0.f};
    f32x4 accP[COLT], accR[COLT];
    #pragma unroll
    for (int t = 0; t < COLT; ++t) { accP[t] = zero; accR[t] = zero; }

    for (int k0 = 0; k0 < DIN; k0 += 32) {
        const float* hp = hrow + k0 + quad * 8;
        float4 h0 = *(const float4*)hp;
        float4 h1 = *(const float4*)(hp + 4);
        float hv[8] = {h0.x, h0.y, h0.z, h0.w, h1.x, h1.y, h1.z, h1.w};
        bf16x8 ahi, alo;
        #pragma unroll
        for (int j = 0; j < 8; ++j) {
            __bf16 hb = (__bf16)hv[j];
            ahi[j] = hb;
            alo[j] = (__bf16)(hv[j] - (float)hb);
        }
        const int kk = k0 + quad * 8;
        #pragma unroll
        for (int t = 0; t < COLT; ++t) {
            const int c = t * 16 + l16;
            bf16x8 bl  = *(const bf16x8*)&lwl [c * SP + kk];
            bf16x8 brh = *(const bf16x8*)&lwrh[c * SP + kk];
            bf16x8 brl = *(const bf16x8*)&lwrl[c * SP + kk];
            accP[t] = __builtin_amdgcn_mfma_f32_16x16x32_bf16(ahi, bl,  accP[t], 0, 0, 0);
            accR[t] = __builtin_amdgcn_mfma_f32_16x16x32_bf16(ahi, brh, accR[t], 0, 0, 0);
            accR[t] = __builtin_amdgcn_mfma_f32_16x16x32_bf16(ahi, brl, accR[t], 0, 0, 0);
            accR[t] = __builtin_amdgcn_mfma_f32_16x16x32_bf16(alo, brh, accR[t], 0, 0, 0);
        }
    }
    // C/D layout: col = lane&15, row = quad*4 + reg  [m89-verified]
    #pragma unroll
    for (int t = 0; t < COLT; ++t) {
        const int c = t * 16 + l16;
        const float bc = bias[c];
        #pragma unroll
        for (int r = 0; r < 4; ++r) {
            int node = n0 + quad * 4 + r;
            if (node < N) {
                Pl[(size_t)node * DOUT + c] = f2bf_rne(accP[t][r]);
                R[(size_t)node * DOUT + c] = accR[t][r] + bc;
            }
        }
    }
}

// ---------------- gather: Hout = relu( mean P[j] + Hout ), P bf16 ----------------

template<int DOUT> struct GatherCfg {
    static constexpr int L   = DOUT / 4;   // uint2s (4 bf16) per node row
    static constexpr int S   = 64 / L;     // nodes concurrently per wave
    static constexpr int M   = 4;          // sequential nodes per subgroup
    static constexpr int NPW = S * M;
    static constexpr int NPB = NPW * 4;    // 4 waves/block
};

template<int DOUT>
__global__ __launch_bounds__(256, 6) void gather_kernel(const unsigned short* __restrict__ P,
                                                        const int* __restrict__ rowptr,
                                                        const int* __restrict__ adj,
                                                        float* __restrict__ Hout, int N) {
    using C = GatherCfg<DOUT>;
    constexpr int L = C::L, S = C::S, M = C::M;
    constexpr int NPW = C::NPW, NPB = C::NPB;
    const int wave = threadIdx.x >> 6, lane = threadIdx.x & 63;
    const int sub = lane / L, cl = lane % L;
    const uint2* __restrict__ P2 = (const uint2*)P;
    float4* __restrict__ H4 = (float4*)Hout;
    const int base = blockIdx.x * NPB + wave * NPW + sub;
    #pragma unroll 1
    for (int m = 0; m < M; ++m) {
        int n = base + m * S;
        if (n >= N) continue;
        int beg = rowptr[n], end = rowptr[n + 1];
        float4 a0 = {0, 0, 0, 0}, a1 = {0, 0, 0, 0}, a2 = {0, 0, 0, 0}, a3 = {0, 0, 0, 0};
        int j = beg;
        while (j < end && (j & 3)) { bfacc(a0, P2[(size_t)adj[j] * L + cl]); ++j; }
        for (; j + 8 <= end; j += 8) {
            int4 sA = *(const int4*)(adj + j);
            int4 sB = *(const int4*)(adj + j + 4);
            uint2 p0 = P2[(size_t)sA.x * L + cl];
            uint2 p1 = P2[(size_t)sA.y * L + cl];
            uint2 p2 = P2[(size_t)sA.z * L + cl];
            uint2 p3 = P2[(size_t)sA.w * L + cl];
            uint2 p4 = P2[(size_t)sB.x * L + cl];
            uint2 p5 = P2[(size_t)sB.y * L + cl];
            uint2 p6 = P2[(size_t)sB.z * L + cl];
            uint2 p7 = P2[(size_t)sB.w * L + cl];
            bfacc(a0, p0); bfacc(a1, p1); bfacc(a2, p2); bfacc(a3, p3);
            bfacc(a0, p4); bfacc(a1, p5); bfacc(a2, p6); bfacc(a3, p7);
        }
        if (j + 4 <= end) {
            int4 sA = *(const int4*)(adj + j);
            bfacc(a0, P2[(size_t)sA.x * L + cl]);
            bfacc(a1, P2[(size_t)sA.y * L + cl]);
            bfacc(a2, P2[(size_t)sA.z * L + cl]);
            bfacc(a3, P2[(size_t)sA.w * L + cl]);
            j += 4;
        }
        for (; j < end; ++j) bfacc(a0, P2[(size_t)adj[j] * L + cl]);
        int deg = end - beg;
        float inv = deg > 0 ? 1.0f / (float)deg : 0.0f;
        float4 r = H4[(size_t)n * L + cl];
        float4 o;
        o.x = fmaxf((a0.x + a1.x + a2.x + a3.x) * inv + r.x, 0.0f);
        o.y = fmaxf((a0.y + a1.y + a2.y + a3.y) * inv + r.y, 0.0f);
        o.z = fmaxf((a0.z + a1.z + a2.z + a3.z) * inv + r.z, 0.0f);
        o.w = fmaxf((a0.w + a1.w + a2.w + a3.w) * inv + r.w, 0.0f);
        H4[(size_t)n * L + cl] = o;
    }
}

__global__ __launch_bounds__(256) void k_head(const float* __restrict__ H3,
                                              const float* __restrict__ Wreg,
                                              const float* __restrict__ breg,
                                              const float* __restrict__ Wcls,
                                              const float* __restrict__ bcls,
                                              float* __restrict__ out, int N) {
    int i = blockIdx.x * 256 + threadIdx.x;
    if (i >= N) return;
    const float4* h = (const float4*)(H3 + (size_t)i * 16);
    float reg = 0.f, cls = 0.f;
    #pragma unroll
    for (int k4 = 0; k4 < 4; ++k4) {
        float4 hv = h[k4];
        float4 wr = ((const float4*)Wreg)[k4];
        float4 wc = ((const float4*)Wcls)[k4];
        reg += hv.x * wr.x + hv.y * wr.y + hv.z * wr.z + hv.w * wr.w;
        cls += hv.x * wc.x + hv.y * wc.y + hv.z * wc.z + hv.w * wc.w;
    }
    out[i] = reg + breg[0];
    out[(size_t)N + i] = cls + bcls[0];
}

extern "C" void kernel_launch(void* const* d_in, const int* in_sizes, int n_in,
                              void* d_out, int out_size, void* d_ws, size_t ws_size,
                              hipStream_t stream) {
    const float* x    = (const float*)d_in[0];
    const int*   ei   = (const int*)d_in[1];
    const float* W1l  = (const float*)d_in[2];
    const float* b1l  = (const float*)d_in[3];
    const float* W1r  = (const float*)d_in[4];
    const float* W2l  = (const float*)d_in[5];
    const float* b2l  = (const float*)d_in[6];
    const float* W2r  = (const float*)d_in[7];
    const float* W3l  = (const float*)d_in[8];
    const float* b3l  = (const float*)d_in[9];
    const float* W3r  = (const float*)d_in[10];
    const float* Wreg = (const float*)d_in[11];
    const float* breg = (const float*)d_in[12];
    const float* Wcls = (const float*)d_in[13];
    const float* bcls = (const float*)d_in[14];

    const int N = in_sizes[0] / 128;
    const int E = in_sizes[1] / 2;
    const int* src = ei;
    const int* dst = ei + E;

    char* ws = (char*)d_ws;
    size_t off = 0;
    auto alloc = [&](size_t bytes) -> void* {
        void* p = ws + off;
        off += (bytes + 255) & ~(size_t)255;
        return p;
    };
    int*   rowptr = (int*)alloc((size_t)(N + 1) * 4);
    int*   bcnt   = (int*)alloc(1024);
    int*   bcur   = (int*)alloc(1024);
    int*   boff   = (int*)alloc(1028);
    int*   adj    = (int*)alloc((size_t)E * 4);
    unsigned short* A = (unsigned short*)alloc((size_t)N * 64 * 2);  // bf16 P
    float* B      = (float*)alloc((size_t)N * 64 * 4);  // h1; doubles as T during CSR build
    float* C      = (float*)alloc((size_t)N * 32 * 4);  // h2
    float* D      = (float*)alloc((size_t)N * 16 * 4);  // h3
    int2*  T      = (int2*)B;                            // E*8B == N*64*4B exactly

    const int NBK = (N + 1023) >> 10;     // buckets (196; must be <= 256)

    // ---- CSR build (atomic-amplification-free) ----
    hipMemsetAsync(bcnt, 0, 1024, stream);
    hipMemsetAsync(bcur, 0, 1024, stream);
    k_bcount<<<1024, 256, 0, stream>>>(dst, E, N, bcnt);
    k_bscan<<<1, 256, 0, stream>>>(bcnt, boff, NBK, E);
    k_bucket<<<(E + BTILE - 1) / BTILE, 256, 0, stream>>>(src, dst, E, N, boff, bcur, T, NBK);
    k_brow<<<NBK, 256, 0, stream>>>(T, boff, rowptr, N, E);
    k_bfill<<<NBK, 256, 0, stream>>>(T, boff, rowptr, adj, N);

    const int PB = 64;   // nodes per proj_mfma block (4 waves x 16)
    constexpr int G64 = GatherCfg<64>::NPB;
    constexpr int G32 = GatherCfg<32>::NPB;
    constexpr int G16 = GatherCfg<16>::NPB;

    // ---- layer 1: 128 -> 64 ----
    proj_mfma<128, 64><<<(N + PB - 1) / PB, 256, 0, stream>>>(x, W1l, W1r, b1l, A, B, N);
    gather_kernel<64><<<(N + G64 - 1) / G64, 256, 0, stream>>>(A, rowptr, adj, B, N);
    // ---- layer 2: 64 -> 32 ----
    proj_mfma<64, 32><<<(N + PB - 1) / PB, 256, 0, stream>>>(B, W2l, W2r, b2l, A, C, N);
    gather_kernel<32><<<(N + G32 - 1) / G32, 256, 0, stream>>>(A, rowptr, adj, C, N);
    // ---- layer 3: 32 -> 16 ----
    proj_mfma<32, 16><<<(N + PB - 1) / PB, 256, 0, stream>>>(C, W3l, W3r, b3l, A, D, N);
    gather_kernel<16><<<(N + G16 - 1) / G16, 256, 0, stream>>>(A, rowptr, adj, D, N);

    // ---- heads ----
    k_head<<<(N + 255) / 256, 256, 0, stream>>>(D, Wreg, breg, Wcls, bcls, (float*)d_out, N);
}

// Round 7
// 745.678 us; speedup vs baseline: 3.4149x; 1.0559x over previous
//
#include <hip/hip_runtime.h>

// ---------------------------------------------------------------------------
// BikeSafetyGNN: 3-layer GraphSAGE (mean) + 2 linear heads, fp32.
// R7: k_brow + k_bfill merged into k_csr @ 1024 threads/block. The old pair
//     ran 196 blocks x 4 waves = 0.77 waves/SIMD (latency-bound, <10% occ).
//     k_csr: LDS histogram -> 1024-wide scan -> rowptr -> LDS-cursor fill,
//     16 waves/block. Everything else unchanged from R6.
// ---------------------------------------------------------------------------

typedef __bf16 bf16x8 __attribute__((ext_vector_type(8)));
typedef float  f32x4  __attribute__((ext_vector_type(4)));

__device__ __forceinline__ unsigned short f2bf_rne(float f) {
    unsigned int u = __float_as_uint(f);
    u = (u + 0x7FFFu + ((u >> 16) & 1u)) >> 16;
    return (unsigned short)u;
}

// unpack 4 bf16 (packed little-endian in uint2) and accumulate into float4
__device__ __forceinline__ void bfacc(float4& a, const uint2 q) {
    a.x += __uint_as_float(q.x << 16);
    a.y += __uint_as_float(q.x & 0xFFFF0000u);
    a.z += __uint_as_float(q.y << 16);
    a.w += __uint_as_float(q.y & 0xFFFF0000u);
}

// ---------------- CSR build (bucket = dst >> 10) ----------------

__global__ __launch_bounds__(256) void k_bcount(const int* __restrict__ dst, int E, int N,
                                                int* __restrict__ bcnt) {
    __shared__ int h[256];
    const int tid = threadIdx.x;
    h[tid] = 0;
    __syncthreads();
    const int stride = gridDim.x * 256;
    for (int i = blockIdx.x * 256 + tid; i < E; i += stride) {
        int d = dst[i];
        d = d < 0 ? 0 : (d >= N ? N - 1 : d);
        atomicAdd(&h[d >> 10], 1);
    }
    __syncthreads();
    if (h[tid]) atomicAdd(&bcnt[tid], h[tid]);
}

__global__ __launch_bounds__(256) void k_bscan(const int* __restrict__ bcnt,
                                               int* __restrict__ boff, int NBK, int E) {
    __shared__ int sd[256];
    const int tid = threadIdx.x;
    int v = (tid < NBK) ? bcnt[tid] : 0;
    sd[tid] = v; __syncthreads();
    for (int off = 1; off < 256; off <<= 1) {
        int t = (tid >= off) ? sd[tid - off] : 0;
        __syncthreads();
        sd[tid] += t;
        __syncthreads();
    }
    if (tid < NBK) boff[tid] = sd[tid] - v;   // exclusive
    if (tid == 0) boff[NBK] = E;
}

// tile-local LDS counting sort of (src,dst) pairs into bucket-contiguous T
#define BTILE 4096
__global__ __launch_bounds__(256) void k_bucket(const int* __restrict__ src,
                                                const int* __restrict__ dst, int E, int N,
                                                const int* __restrict__ boff,
                                                int* __restrict__ bcur,
                                                int2* __restrict__ T, int NBK) {
    __shared__ int cnt[256], cnt2[256], lofs[256], gbase[256], boffs[256], sd[256];
    __shared__ int2 staged[BTILE];
    const int tid = threadIdx.x;
    const int tb = blockIdx.x * BTILE;
    const int tn = min(BTILE, E - tb);
    cnt[tid] = 0; cnt2[tid] = 0;
    boffs[tid] = (tid < NBK) ? boff[tid] : 0;
    __syncthreads();
    for (int i = tid; i < tn; i += 256) {
        int d = dst[tb + i];
        d = d < 0 ? 0 : (d >= N ? N - 1 : d);
        atomicAdd(&cnt[d >> 10], 1);
    }
    __syncthreads();
    int v = cnt[tid];
    sd[tid] = v; __syncthreads();
    for (int off = 1; off < 256; off <<= 1) {
        int t = (tid >= off) ? sd[tid - off] : 0;
        __syncthreads();
        sd[tid] += t;
        __syncthreads();
    }
    lofs[tid] = sd[tid] - v;
    if (v > 0 && tid < NBK) gbase[tid] = atomicAdd(&bcur[tid], v);
    __syncthreads();
    for (int i = tid; i < tn; i += 256) {
        int d = dst[tb + i];
        d = d < 0 ? 0 : (d >= N ? N - 1 : d);
        int s = src[tb + i];
        s = s < 0 ? 0 : (s >= N ? N - 1 : s);
        int b = d >> 10;
        int r = atomicAdd(&cnt2[b], 1);
        staged[lofs[b] + r] = make_int2(s, d);
    }
    __syncthreads();
    for (int i = tid; i < tn; i += 256) {
        int2 p = staged[i];
        int b = p.y >> 10;
        T[(size_t)boffs[b] + gbase[b] + (i - lofs[b])] = p;
    }
}

// per bucket: LDS degree histogram + 1024-wide scan -> rowptr, then LDS-cursor
// fill of adj. One block of 1024 threads per bucket (16 waves -> ~3 waves/SIMD
// across the grid, vs 0.77 for the old 256-thread brow/bfill pair).
__global__ __launch_bounds__(1024) void k_csr(const int2* __restrict__ T,
                                              const int* __restrict__ boff,
                                              int* __restrict__ rowptr,
                                              int* __restrict__ adj, int N, int E) {
    __shared__ int hist[1024];
    __shared__ int sc[1024];
    const int tid = threadIdx.x;
    const int b = blockIdx.x;
    const int node0 = b << 10;
    hist[tid] = 0;
    __syncthreads();
    const int beg = boff[b], end = boff[b + 1];
    for (int i = beg + tid; i < end; i += 1024)
        atomicAdd(&hist[T[i].y - node0], 1);
    __syncthreads();
    // exclusive scan (Hillis-Steele over 1024)
    int v = hist[tid];
    sc[tid] = v;
    __syncthreads();
    for (int off = 1; off < 1024; off <<= 1) {
        int t = (tid >= off) ? sc[tid - off] : 0;
        __syncthreads();
        sc[tid] += t;
        __syncthreads();
    }
    const int excl = beg + sc[tid] - v;   // absolute start for node node0+tid
    const int n = node0 + tid;
    if (n < N) rowptr[n] = excl;
    if (b == 0 && tid == 0) rowptr[N] = E;
    hist[tid] = excl;                      // reuse as running cursor
    __syncthreads();
    for (int i = beg + tid; i < end; i += 1024) {
        int2 p = T[i];
        int pos = atomicAdd(&hist[p.y - node0], 1);
        adj[pos] = p.x;
    }
}

// ---------------- MFMA fused projection ----------------
// Pl = bf16(hi(H) @ bf16(Wl)^T);  R = hi@Wrh + hi@Wrl + lo@Wrh + bias
// One wave = 16 nodes x DOUT cols. 4 waves/block = 64 nodes/block.
template<int DIN, int DOUT>
__global__ __launch_bounds__(256) void proj_mfma(const float* __restrict__ H,
                                                 const float* __restrict__ Wl,
                                                 const float* __restrict__ Wr,
                                                 const float* __restrict__ bias,
                                                 unsigned short* __restrict__ Pl,
                                                 float* __restrict__ R, int N) {
    constexpr int SP = DIN + 8;       // padded LDS row stride (bf16 elems)
    constexpr int COLT = DOUT / 16;   // 16-col tiles
    __shared__ __bf16 lwl[DOUT * SP];
    __shared__ __bf16 lwrh[DOUT * SP];
    __shared__ __bf16 lwrl[DOUT * SP];
    for (int idx = threadIdx.x; idx < DIN * DOUT; idx += 256) {
        int c = idx / DIN, k = idx % DIN;
        float wl = Wl[idx], wr = Wr[idx];
        __bf16 wrh = (__bf16)wr;
        lwl[c * SP + k] = (__bf16)wl;
        lwrh[c * SP + k] = wrh;
        lwrl[c * SP + k] = (__bf16)(wr - (float)wrh);
    }
    __syncthreads();
    const int wave = threadIdx.x >> 6, lane = threadIdx.x & 63;
    const int quad = lane >> 4, l16 = lane & 15;
    const int n0 = (blockIdx.x * 4 + wave) * 16;
    int arow = n0 + l16;
    if (arow >= N) arow = N - 1;
    const float* hrow = H + (size_t)arow * DIN;

    f32x4 zero = {0.f, 0.f, 0.f, 0.f};
    f32x4 accP[COLT], accR[COLT];
    #pragma unroll
    for (int t = 0; t < COLT; ++t) { accP[t] = zero; accR[t] = zero; }

    for (int k0 = 0; k0 < DIN; k0 += 32) {
        const float* hp = hrow + k0 + quad * 8;
        float4 h0 = *(const float4*)hp;
        float4 h1 = *(const float4*)(hp + 4);
        float hv[8] = {h0.x, h0.y, h0.z, h0.w, h1.x, h1.y, h1.z, h1.w};
        bf16x8 ahi, alo;
        #pragma unroll
        for (int j = 0; j < 8; ++j) {
            __bf16 hb = (__bf16)hv[j];
            ahi[j] = hb;
            alo[j] = (__bf16)(hv[j] - (float)hb);
        }
        const int kk = k0 + quad * 8;
        #pragma unroll
        for (int t = 0; t < COLT; ++t) {
            const int c = t * 16 + l16;
            bf16x8 bl  = *(const bf16x8*)&lwl [c * SP + kk];
            bf16x8 brh = *(const bf16x8*)&lwrh[c * SP + kk];
            bf16x8 brl = *(const bf16x8*)&lwrl[c * SP + kk];
            accP[t] = __builtin_amdgcn_mfma_f32_16x16x32_bf16(ahi, bl,  accP[t], 0, 0, 0);
            accR[t] = __builtin_amdgcn_mfma_f32_16x16x32_bf16(ahi, brh, accR[t], 0, 0, 0);
            accR[t] = __builtin_amdgcn_mfma_f32_16x16x32_bf16(ahi, brl, accR[t], 0, 0, 0);
            accR[t] = __builtin_amdgcn_mfma_f32_16x16x32_bf16(alo, brh, accR[t], 0, 0, 0);
        }
    }
    // C/D layout: col = lane&15, row = quad*4 + reg  [m89-verified]
    #pragma unroll
    for (int t = 0; t < COLT; ++t) {
        const int c = t * 16 + l16;
        const float bc = bias[c];
        #pragma unroll
        for (int r = 0; r < 4; ++r) {
            int node = n0 + quad * 4 + r;
            if (node < N) {
                Pl[(size_t)node * DOUT + c] = f2bf_rne(accP[t][r]);
                R[(size_t)node * DOUT + c] = accR[t][r] + bc;
            }
        }
    }
}

// ---------------- gather: Hout = relu( mean P[j] + Hout ), P bf16 ----------------

template<int DOUT> struct GatherCfg {
    static constexpr int L   = DOUT / 4;   // uint2s (4 bf16) per node row
    static constexpr int S   = 64 / L;     // nodes concurrently per wave
    static constexpr int M   = 4;          // sequential nodes per subgroup
    static constexpr int NPW = S * M;
    static constexpr int NPB = NPW * 4;    // 4 waves/block
};

template<int DOUT>
__global__ __launch_bounds__(256, 6) void gather_kernel(const unsigned short* __restrict__ P,
                                                        const int* __restrict__ rowptr,
                                                        const int* __restrict__ adj,
                                                        float* __restrict__ Hout, int N) {
    using C = GatherCfg<DOUT>;
    constexpr int L = C::L, S = C::S, M = C::M;
    constexpr int NPW = C::NPW, NPB = C::NPB;
    const int wave = threadIdx.x >> 6, lane = threadIdx.x & 63;
    const int sub = lane / L, cl = lane % L;
    const uint2* __restrict__ P2 = (const uint2*)P;
    float4* __restrict__ H4 = (float4*)Hout;
    const int base = blockIdx.x * NPB + wave * NPW + sub;
    #pragma unroll 1
    for (int m = 0; m < M; ++m) {
        int n = base + m * S;
        if (n >= N) continue;
        int beg = rowptr[n], end = rowptr[n + 1];
        float4 a0 = {0, 0, 0, 0}, a1 = {0, 0, 0, 0}, a2 = {0, 0, 0, 0}, a3 = {0, 0, 0, 0};
        int j = beg;
        while (j < end && (j & 3)) { bfacc(a0, P2[(size_t)adj[j] * L + cl]); ++j; }
        for (; j + 8 <= end; j += 8) {
            int4 sA = *(const int4*)(adj + j);
            int4 sB = *(const int4*)(adj + j + 4);
            uint2 p0 = P2[(size_t)sA.x * L + cl];
            uint2 p1 = P2[(size_t)sA.y * L + cl];
            uint2 p2 = P2[(size_t)sA.z * L + cl];
            uint2 p3 = P2[(size_t)sA.w * L + cl];
            uint2 p4 = P2[(size_t)sB.x * L + cl];
            uint2 p5 = P2[(size_t)sB.y * L + cl];
            uint2 p6 = P2[(size_t)sB.z * L + cl];
            uint2 p7 = P2[(size_t)sB.w * L + cl];
            bfacc(a0, p0); bfacc(a1, p1); bfacc(a2, p2); bfacc(a3, p3);
            bfacc(a0, p4); bfacc(a1, p5); bfacc(a2, p6); bfacc(a3, p7);
        }
        if (j + 4 <= end) {
            int4 sA = *(const int4*)(adj + j);
            bfacc(a0, P2[(size_t)sA.x * L + cl]);
            bfacc(a1, P2[(size_t)sA.y * L + cl]);
            bfacc(a2, P2[(size_t)sA.z * L + cl]);
            bfacc(a3, P2[(size_t)sA.w * L + cl]);
            j += 4;
        }
        for (; j < end; ++j) bfacc(a0, P2[(size_t)adj[j] * L + cl]);
        int deg = end - beg;
        float inv = deg > 0 ? 1.0f / (float)deg : 0.0f;
        float4 r = H4[(size_t)n * L + cl];
        float4 o;
        o.x = fmaxf((a0.x + a1.x + a2.x + a3.x) * inv + r.x, 0.0f);
        o.y = fmaxf((a0.y + a1.y + a2.y + a3.y) * inv + r.y, 0.0f);
        o.z = fmaxf((a0.z + a1.z + a2.z + a3.z) * inv + r.z, 0.0f);
        o.w = fmaxf((a0.w + a1.w + a2.w + a3.w) * inv + r.w, 0.0f);
        H4[(size_t)n * L + cl] = o;
    }
}

__global__ __launch_bounds__(256) void k_head(const float* __restrict__ H3,
                                              const float* __restrict__ Wreg,
                                              const float* __restrict__ breg,
                                              const float* __restrict__ Wcls,
                                              const float* __restrict__ bcls,
                                              float* __restrict__ out, int N) {
    int i = blockIdx.x * 256 + threadIdx.x;
    if (i >= N) return;
    const float4* h = (const float4*)(H3 + (size_t)i * 16);
    float reg = 0.f, cls = 0.f;
    #pragma unroll
    for (int k4 = 0; k4 < 4; ++k4) {
        float4 hv = h[k4];
        float4 wr = ((const float4*)Wreg)[k4];
        float4 wc = ((const float4*)Wcls)[k4];
        reg += hv.x * wr.x + hv.y * wr.y + hv.z * wr.z + hv.w * wr.w;
        cls += hv.x * wc.x + hv.y * wc.y + hv.z * wc.z + hv.w * wc.w;
    }
    out[i] = reg + breg[0];
    out[(size_t)N + i] = cls + bcls[0];
}

extern "C" void kernel_launch(void* const* d_in, const int* in_sizes, int n_in,
                              void* d_out, int out_size, void* d_ws, size_t ws_size,
                              hipStream_t stream) {
    const float* x    = (const float*)d_in[0];
    const int*   ei   = (const int*)d_in[1];
    const float* W1l  = (const float*)d_in[2];
    const float* b1l  = (const float*)d_in[3];
    const float* W1r  = (const float*)d_in[4];
    const float* W2l  = (const float*)d_in[5];
    const float* b2l  = (const float*)d_in[6];
    const float* W2r  = (const float*)d_in[7];
    const float* W3l  = (const float*)d_in[8];
    const float* b3l  = (const float*)d_in[9];
    const float* W3r  = (const float*)d_in[10];
    const float* Wreg = (const float*)d_in[11];
    const float* breg = (const float*)d_in[12];
    const float* Wcls = (const float*)d_in[13];
    const float* bcls = (const float*)d_in[14];

    const int N = in_sizes[0] / 128;
    const int E = in_sizes[1] / 2;
    const int* src = ei;
    const int* dst = ei + E;

    char* ws = (char*)d_ws;
    size_t off = 0;
    auto alloc = [&](size_t bytes) -> void* {
        void* p = ws + off;
        off += (bytes + 255) & ~(size_t)255;
        return p;
    };
    int*   rowptr = (int*)alloc((size_t)(N + 1) * 4);
    int*   bcnt   = (int*)alloc(1024);
    int*   bcur   = (int*)alloc(1024);
    int*   boff   = (int*)alloc(1028);
    int*   adj    = (int*)alloc((size_t)E * 4);
    unsigned short* A = (unsigned short*)alloc((size_t)N * 64 * 2);  // bf16 P
    float* B      = (float*)alloc((size_t)N * 64 * 4);  // h1; doubles as T during CSR build
    float* C      = (float*)alloc((size_t)N * 32 * 4);  // h2
    float* D      = (float*)alloc((size_t)N * 16 * 4);  // h3
    int2*  T      = (int2*)B;                            // E*8B == N*64*4B exactly

    const int NBK = (N + 1023) >> 10;     // buckets (196; must be <= 256)

    // ---- CSR build (atomic-amplification-free) ----
    hipMemsetAsync(bcnt, 0, 1024, stream);
    hipMemsetAsync(bcur, 0, 1024, stream);
    k_bcount<<<1024, 256, 0, stream>>>(dst, E, N, bcnt);
    k_bscan<<<1, 256, 0, stream>>>(bcnt, boff, NBK, E);
    k_bucket<<<(E + BTILE - 1) / BTILE, 256, 0, stream>>>(src, dst, E, N, boff, bcur, T, NBK);
    k_csr<<<NBK, 1024, 0, stream>>>(T, boff, rowptr, adj, N, E);

    const int PB = 64;   // nodes per proj_mfma block (4 waves x 16)
    constexpr int G64 = GatherCfg<64>::NPB;
    constexpr int G32 = GatherCfg<32>::NPB;
    constexpr int G16 = GatherCfg<16>::NPB;

    // ---- layer 1: 128 -> 64 ----
    proj_mfma<128, 64><<<(N + PB - 1) / PB, 256, 0, stream>>>(x, W1l, W1r, b1l, A, B, N);
    gather_kernel<64><<<(N + G64 - 1) / G64, 256, 0, stream>>>(A, rowptr, adj, B, N);
    // ---- layer 2: 64 -> 32 ----
    proj_mfma<64, 32><<<(N + PB - 1) / PB, 256, 0, stream>>>(B, W2l, W2r, b2l, A, C, N);
    gather_kernel<32><<<(N + G32 - 1) / G32, 256, 0, stream>>>(A, rowptr, adj, C, N);
    // ---- layer 3: 32 -> 16 ----
    proj_mfma<32, 16><<<(N + PB - 1) / PB, 256, 0, stream>>>(C, W3l, W3r, b3l, A, D, N);
    gather_kernel<16><<<(N + G16 - 1) / G16, 256, 0, stream>>>(A, rowptr, adj, D, N);

    // ---- heads ----
    k_head<<<(N + 255) / 256, 256, 0, stream>>>(D, Wreg, breg, Wcls, bcls, (float*)d_out, N);
}